// Round 22
// baseline (96.823 us; speedup 1.0000x reference)
//
#include <hip/hip_runtime.h>
#include <math.h>

#define BATCH 2048

typedef __attribute__((ext_vector_type(4))) int i32x4;
typedef __attribute__((ext_vector_type(16))) int i32x16;

__device__ __forceinline__ int sdot4(int a, int b, int c) {
    return __builtin_amdgcn_sdot4(a, b, c, false);
}

__device__ __forceinline__ float fsign(float v) {
    return v > 0.f ? 1.f : (v < 0.f ? -1.f : 0.f);
}

// act swizzle (T2): flips addr bits 4-6 by pixel bits 2-4; bijective on [0,9248),
// keeps 16B chunks intact, independent of the low 5 bits (oc).
__device__ __forceinline__ int aswz(int off) {
    return off ^ (((off >> 7) & 7) << 4);
}

// Fused prep: wf1 binarize | w2 pack [tap][half][oc][16] | wf2 binarize
__global__ void prep_all(const float* __restrict__ w2, const float* __restrict__ wf1,
                         const float* __restrict__ wf2,
                         signed char* __restrict__ w2p, signed char* __restrict__ wf1s,
                         signed char* __restrict__ wf2p) {
    int i = blockIdx.x * 256 + threadIdx.x;
    if (i < 2359296) {  // wf1 sign (natural [1024][2304] layout)
        float v = wf1[i];
        wf1s[i] = v > 0.f ? 1 : (v < 0.f ? -1 : 0);
        return;
    }
    i -= 2359296;
    if (i < 51200) {    // w2 [64][32][5][5] -> w2p [25 tap][2 khalf][64 oc][16 ic]
        int tap = i >> 11;
        int r = i & 2047;
        int half = r >> 10;
        int r2 = r & 1023;
        int oc = r2 >> 4, j = r2 & 15;
        int ic = half * 16 + j;
        float v = w2[(oc * 32 + ic) * 25 + tap];
        w2p[i] = v > 0.f ? 1 : (v < 0.f ? -1 : 0);
        return;
    }
    i -= 51200;
    if (i < 10240) {    // wf2 sign
        float v = wf2[i];
        wf2p[i] = v > 0.f ? 1 : (v < 0.f ? -1 : 0);
    }
}

// K12: conv1(+BN+sign+pool) fused into conv2 MFMA. Block = 8 images, 12 waves.
// conv1 phase: wave-uniform cell loop (scalar index math + uniform-base loads
// with immediate offsets); lane = (oc, window-row-half), 18 FMA/lane,
// cross-half max via shfl_xor(32). MFMA phase = r21 verbatim.
#define K2_IMG_STRIDE 9248          // 17*17*32
#define K2_WOFF 73984               // 8*9248
__global__ __launch_bounds__(768) void k12_fused(
        const float* __restrict__ x,
        const float* __restrict__ w1, const float* __restrict__ b1,
        const float* __restrict__ g1, const float* __restrict__ be1,
        const float* __restrict__ m1, const float* __restrict__ v1,
        const signed char* __restrict__ w2p,
        const float* __restrict__ b2, const float* __restrict__ g2,
        const float* __restrict__ be2, const float* __restrict__ m2,
        const float* __restrict__ v2, signed char* __restrict__ act2) {
    __shared__ __align__(16) signed char smem[125184];
    int tid = threadIdx.x;
    int b0 = blockIdx.x * 8;

    // ---- phase 0: zero whole act region (borders stay 0), stage weights ----
    {
        i32x4 z4 = {0, 0, 0, 0};
        i32x4* s4 = (i32x4*)smem;
        for (int i = tid; i < 4624; i += 768) s4[i] = z4;
        const i32x4* wsrc = (const i32x4*)w2p;
        i32x4* w4 = (i32x4*)(smem + K2_WOFF);
        for (int i = tid; i < 3200; i += 768) w4[i] = wsrc[i];
    }
    __syncthreads();

    // ---- phase 1: conv1 + BN + sign + pool2 -> act LDS bytes (swizzled) ----
    {
        int wv = __builtin_amdgcn_readfirstlane(tid >> 6);   // 0..11, uniform
        int lane = tid & 63;
        int oc = lane & 31, half = lane >> 5;                // window-row half
        float sw[9];
#pragma unroll
        for (int i = 0; i < 9; i++) sw[i] = fsign(w1[oc * 9 + i]);
        float bias = b1[oc], mm = m1[oc];
        float sc = g1[oc] / sqrtf(v1[oc] + 1e-5f), bb = be1[oc];
        int vroff = half * 112;              // lane row-offset in bytes

        for (int it = 0; it < 113; ++it) {
            int cell = wv + 12 * it;         // uniform: 0..1351 (8 img x 169)
            if (cell < 1352) {
                int img = cell / 169, pix = cell - img * 169;   // scalar math
                int py = pix / 13, px = pix - py * 13;
                const char* base =
                    (const char*)(x + (size_t)(b0 + img) * 784 + py * 56 + px * 2)
                    + vroff;                 // uniform base + lane half-offset
                float2 r0a = *(const float2*)(base + 0);
                float2 r0b = *(const float2*)(base + 8);
                float2 r1a = *(const float2*)(base + 112);
                float2 r1b = *(const float2*)(base + 120);
                float2 r2a = *(const float2*)(base + 224);
                float2 r2b = *(const float2*)(base + 232);
                float xr[3][4];
                xr[0][0] = r0a.x; xr[0][1] = r0a.y; xr[0][2] = r0b.x; xr[0][3] = r0b.y;
                xr[1][0] = r1a.x; xr[1][1] = r1a.y; xr[1][2] = r1b.x; xr[1][3] = r1b.y;
                xr[2][0] = r2a.x; xr[2][1] = r2a.y; xr[2][2] = r2b.x; xr[2][3] = r2b.y;
                // windows (dyp=half, dxp=0) and (dyp=half, dxp=1); same sum order
                float acc0 = 0.f, acc1 = 0.f;
#pragma unroll
                for (int ky = 0; ky < 3; ky++)
#pragma unroll
                    for (int kx = 0; kx < 3; kx++) {
                        acc0 += xr[ky][kx] * sw[ky * 3 + kx];
                        acc1 += xr[ky][kx + 1] * sw[ky * 3 + kx];
                    }
                float mx2 = fmaxf(acc0, acc1);
                float oth = __shfl_xor(mx2, 32);
                float maxacc = fmaxf(mx2, oth);     // max over all 4 windows
                float bn = (maxacc + bias - mm) * sc + bb;  // BN monotone (sc>0)
                if (!half) {
                    int p32 = ((py + 2) * 17 + (px + 2)) * 32;
                    smem[img * K2_IMG_STRIDE + aswz(p32 + oc)] = (signed char)fsign(bn);
                }
            }
        }
    }
    __syncthreads();

    // ---- phase 2: conv2 MFMA (r21 verbatim) ----
    int wave = tid >> 6, lane = tid & 63;
    int lrow = lane & 31, kh = lane >> 5;
    const signed char* wbase = smem + K2_WOFF + kh * 1024 + lrow * 16;

    const signed char* aimg[3];
    int pixbase[3];
#pragma unroll
    for (int t = 0; t < 3; ++t) {
        int mt = wave * 3 + t;                // 0..35
        int m = mt * 32 + lrow;
        int q = m >> 2, j = m & 3;
        int img = q / 36, qq = q - img * 36;
        int oy = 2 * (qq / 6) + (j >> 1);
        int ox = 2 * (qq - (qq / 6) * 6) + (j & 1);
        aimg[t] = smem + img * K2_IMG_STRIDE;
        pixbase[t] = oy * 17 + ox;
    }

    i32x16 acc[3][2] = {};
#pragma unroll 5
    for (int tap = 0; tap < 25; ++tap) {
        int ky = tap / 5, kx = tap - (tap / 5) * 5;
        i32x4 w0 = *(const i32x4*)(wbase + tap * 2048);        // oc = lrow
        i32x4 w1v = *(const i32x4*)(wbase + tap * 2048 + 512); // oc = 32+lrow
#pragma unroll
        for (int t = 0; t < 3; ++t) {
            int off = (pixbase[t] + ky * 17 + kx) * 32 + kh * 16;
            i32x4 a = *(const i32x4*)(aimg[t] + aswz(off));
            acc[t][0] = __builtin_amdgcn_mfma_i32_32x32x32_i8(a, w0, acc[t][0], 0, 0, 0);
            acc[t][1] = __builtin_amdgcn_mfma_i32_32x32x32_i8(a, w1v, acc[t][1], 0, 0, 0);
        }
    }
    __syncthreads();   // all LDS A/W reads done -> act region reusable

    // epilogue: BN+sign+pool -> LDS [img][oc][36], then coalesced copy-out
    float bi[2], mm2[2], sc2[2], bb2[2];
#pragma unroll
    for (int h = 0; h < 2; ++h) {
        int oc = h * 32 + lrow;
        bi[h] = b2[oc]; mm2[h] = m2[oc];
        sc2[h] = g2[oc] / sqrtf(v2[oc] + 1e-5f); bb2[h] = be2[oc];
    }
#pragma unroll
    for (int t = 0; t < 3; ++t) {
        int mt = wave * 3 + t;
#pragma unroll
        for (int h = 0; h < 2; ++h) {
            int oc = h * 32 + lrow;
#pragma unroll
            for (int g = 0; g < 4; g++) {
                int qo = mt * 8 + kh + 2 * g;     // pool cell 0..287 (8 images)
                int imo = qo / 36, qqo = qo - imo * 36;
                float best = -2.f;
#pragma unroll
                for (int jj = 0; jj < 4; jj++) {
                    float z = (float)acc[t][h][g * 4 + jj] + bi[h];
                    float bn = (z - mm2[h]) * sc2[h] + bb2[h];
                    best = fmaxf(best, fsign(bn));
                }
                smem[imo * 2304 + oc * 36 + qqo] = (signed char)best;
            }
        }
    }
    __syncthreads();
    {
        const i32x4* s4o = (const i32x4*)smem;
        i32x4* dst = (i32x4*)(act2 + (size_t)b0 * 2304);
        for (int i = tid; i < 1152; i += 768) dst[i] = s4o[i];
    }
}

// K3: fc1 as LDS-tiled MFMA i8 GEMM 2048x1024x2304. (r21 verbatim)
#define K3A_SEG 2064                // 128*16 + 16 pad
#define K3B_SEG 1040                // 64*16 + 16 pad
#define K3_BOFF 16512               // 8 * 2064
__global__ __launch_bounds__(256) void k3_mfma(
        const signed char* __restrict__ act2, const signed char* __restrict__ wf1s,
        const float* __restrict__ bf1, const float* __restrict__ gf1,
        const float* __restrict__ bef1, const float* __restrict__ mf1,
        const float* __restrict__ vf1, signed char* __restrict__ act3) {
    __shared__ __align__(16) signed char s[K3_BOFF + 8 * K3B_SEG];  // 24832
    int tid = threadIdx.x;
    int bid = blockIdx.x;
    int tn = bid & 15, tm = bid >> 4;

    const signed char* Ab = act2 + (size_t)tm * 128 * 2304;
    const signed char* Bb = wf1s + (size_t)tn * 64 * 2304;
    size_t gA[4]; int lwA[4];
#pragma unroll
    for (int i = 0; i < 4; i++) {
        int e = tid + 256 * i, row = e >> 3, sg = (e + row) & 7;
        gA[i] = (size_t)row * 2304 + sg * 16;
        lwA[i] = sg * K3A_SEG + row * 16;
    }
    size_t gB[2]; int lwB[2];
#pragma unroll
    for (int i = 0; i < 2; i++) {
        int e = tid + 256 * i, row = e >> 3, sg = (e + row) & 7;
        gB[i] = (size_t)row * 2304 + sg * 16;
        lwB[i] = K3_BOFF + sg * K3B_SEG + row * 16;
    }

    i32x4 ra[4], rb[2];
#pragma unroll
    for (int i = 0; i < 4; i++) ra[i] = *(const i32x4*)(Ab + gA[i]);
#pragma unroll
    for (int i = 0; i < 2; i++) rb[i] = *(const i32x4*)(Bb + gB[i]);

    int l = tid & 63, wid = tid >> 6;
    int lrow = l & 31, kh = l >> 5;
    int raddrA = kh * K3A_SEG + (wid * 32 + lrow) * 16;
    int raddrB0 = K3_BOFF + kh * K3B_SEG + lrow * 16;
    int raddrB1 = raddrB0 + 32 * 16;

    i32x16 acc0 = {0};
    i32x16 acc1 = {0};
    for (int t = 0; t < 18; ++t) {
        if (t) __syncthreads();
#pragma unroll
        for (int i = 0; i < 4; i++) *(i32x4*)(s + lwA[i]) = ra[i];
#pragma unroll
        for (int i = 0; i < 2; i++) *(i32x4*)(s + lwB[i]) = rb[i];
        if (t < 17) {
            size_t ko = (size_t)(t + 1) * 128;
#pragma unroll
            for (int i = 0; i < 4; i++) ra[i] = *(const i32x4*)(Ab + gA[i] + ko);
#pragma unroll
            for (int i = 0; i < 2; i++) rb[i] = *(const i32x4*)(Bb + gB[i] + ko);
        }
        __syncthreads();
#pragma unroll
        for (int ks = 0; ks < 4; ++ks) {
            i32x4 a  = *(const i32x4*)(s + raddrA + ks * 2 * K3A_SEG);
            i32x4 b0 = *(const i32x4*)(s + raddrB0 + ks * 2 * K3B_SEG);
            i32x4 b1 = *(const i32x4*)(s + raddrB1 + ks * 2 * K3B_SEG);
            acc0 = __builtin_amdgcn_mfma_i32_32x32x32_i8(a, b0, acc0, 0, 0, 0);
            acc1 = __builtin_amdgcn_mfma_i32_32x32x32_i8(a, b1, acc1, 0, 0, 0);
        }
    }

    int col0 = tn * 64 + lrow;
    int col1 = col0 + 32;
    float bi0 = bf1[col0], m0 = mf1[col0];
    float sc0 = gf1[col0] / sqrtf(vf1[col0] + 1e-5f), bb0 = bef1[col0];
    float bi1 = bf1[col1], m1 = mf1[col1];
    float sc1 = gf1[col1] / sqrtf(vf1[col1] + 1e-5f), bb1 = bef1[col1];
    __syncthreads();   // K-loop reads of s done -> reuse as output tile [128][64]
#pragma unroll
    for (int r = 0; r < 16; r++) {
        int rowl = wid * 32 + (r & 3) + 8 * (r >> 2) + 4 * kh;
        float bn0 = ((float)acc0[r] + bi0 - m0) * sc0 + bb0;
        float bn1 = ((float)acc1[r] + bi1 - m1) * sc1 + bb1;
        s[rowl * 64 + lrow] = (signed char)fsign(bn0);
        s[rowl * 64 + lrow + 32] = (signed char)fsign(bn1);
    }
    __syncthreads();
    for (int i = tid; i < 512; i += 256) {
        int rl = i >> 2, c16 = i & 3;
        *(i32x4*)(act3 + (size_t)(tm * 128 + rl) * 1024 + tn * 64 + c16 * 16) =
            *(const i32x4*)(s + i * 16);
    }
}

// K4: fc2 (1024->10) + bias + BN + log_softmax. One wave per image. (unchanged)
__global__ void k4_fc2(const signed char* __restrict__ act3, const signed char* __restrict__ swf2,
                       const float* __restrict__ bf2, const float* __restrict__ gf2,
                       const float* __restrict__ bef2, const float* __restrict__ mf2,
                       const float* __restrict__ vf2, float* __restrict__ out) {
    int wid = (blockIdx.x * 256 + threadIdx.x) >> 6;
    int lane = threadIdx.x & 63;
    if (wid >= BATCH) return;
    const int* hd = (const int*)act3 + (size_t)wid * 256;
    const int* wd = (const int*)swf2;
    int acc[10];
#pragma unroll
    for (int o = 0; o < 10; o++) acc[o] = 0;
#pragma unroll
    for (int i = 0; i < 4; i++) {
        int k4 = i * 64 + lane;
        int hv = hd[k4];
#pragma unroll
        for (int o = 0; o < 10; o++)
            acc[o] = sdot4(hv, wd[o * 256 + k4], acc[o]);
    }
#pragma unroll
    for (int o = 0; o < 10; o++)
#pragma unroll
        for (int s = 32; s > 0; s >>= 1) acc[o] += __shfl_xor(acc[o], s);
    if (lane == 0) {
        float logit[10];
        float mx = -1e30f;
#pragma unroll
        for (int o = 0; o < 10; o++) {
            float z = (float)acc[o] + bf2[o];
            float bn = (z - mf2[o]) * (gf2[o] / sqrtf(vf2[o] + 1e-5f)) + bef2[o];
            logit[o] = bn;
            mx = fmaxf(mx, bn);
        }
        float s = 0.f;
#pragma unroll
        for (int o = 0; o < 10; o++) s += expf(logit[o] - mx);
        float lse = mx + logf(s);
#pragma unroll
        for (int o = 0; o < 10; o++) out[(size_t)wid * 10 + o] = logit[o] - lse;
    }
}

extern "C" void kernel_launch(void* const* d_in, const int* in_sizes, int n_in,
                              void* d_out, int out_size, void* d_ws, size_t ws_size,
                              hipStream_t stream) {
    const float* x   = (const float*)d_in[0];
    const float* w1  = (const float*)d_in[1];
    const float* b1  = (const float*)d_in[2];
    const float* g1  = (const float*)d_in[3];
    const float* be1 = (const float*)d_in[4];
    const float* m1  = (const float*)d_in[5];
    const float* v1  = (const float*)d_in[6];
    const float* w2  = (const float*)d_in[7];
    const float* b2  = (const float*)d_in[8];
    const float* g2  = (const float*)d_in[9];
    const float* be2 = (const float*)d_in[10];
    const float* m2  = (const float*)d_in[11];
    const float* v2  = (const float*)d_in[12];
    const float* wf1 = (const float*)d_in[13];
    const float* bf1 = (const float*)d_in[14];
    const float* gf1 = (const float*)d_in[15];
    const float* bef1= (const float*)d_in[16];
    const float* mf1 = (const float*)d_in[17];
    const float* vf1 = (const float*)d_in[18];
    const float* wf2 = (const float*)d_in[19];
    const float* bf2 = (const float*)d_in[20];
    const float* gf2 = (const float*)d_in[21];
    const float* bef2= (const float*)d_in[22];
    const float* mf2 = (const float*)d_in[23];
    const float* vf2 = (const float*)d_in[24];
    float* out = (float*)d_out;

    // ws layout (all int8)
    char* ws = (char*)d_ws;
    signed char* act2 = (signed char*)ws;                  // 2048*2304     =  4,718,592
    signed char* act3 = act2 + 4718592;                    // 2048*1024     =  2,097,152
    signed char* w2p  = act3 + 2097152;                    // 25*2*64*16    =     51,200
    signed char* wf1s = w2p + 51200;                       // 1024*2304     =  2,359,296
    signed char* wf2p = wf1s + 2359296;                    // 10*1024       =     10,240

    // prep: 2,359,296 + 51,200 + 10,240 = 2,420,736 elems -> 9456 blocks exact
    prep_all<<<9456, 256, 0, stream>>>(w2, wf1, wf2, w2p, wf1s, wf2p);

    k12_fused<<<256, 768, 0, stream>>>(x, w1, b1, g1, be1, m1, v1,
                                       w2p, b2, g2, be2, m2, v2, act2);

    k3_mfma<<<256, 256, 0, stream>>>(act2, wf1s, bf1, gf1, bef1, mf1, vf1, act3);

    k4_fc2<<<512, 256, 0, stream>>>(act3, wf2p, bf2, gf2, bef2, mf2, vf2, out);
}

// Round 23
// 73.619 us; speedup vs baseline: 1.3152x; 1.3152x over previous
//
#include <hip/hip_runtime.h>
#include <math.h>

#define BATCH 2048

typedef __attribute__((ext_vector_type(4))) int i32x4;
typedef __attribute__((ext_vector_type(16))) int i32x16;

__device__ __forceinline__ int sdot4(int a, int b, int c) {
    return __builtin_amdgcn_sdot4(a, b, c, false);
}

__device__ __forceinline__ float fsign(float v) {
    return v > 0.f ? 1.f : (v < 0.f ? -1.f : 0.f);
}

// act swizzle (T2): flips addr bits 4-6 by pixel bits 2-4; bijective on [0,9248),
// keeps 16B chunks intact, independent of the low 5 bits (oc).
__device__ __forceinline__ int aswz(int off) {
    return off ^ (((off >> 7) & 7) << 4);
}

// K1 + prep fused: each block first does 1182 prep elements (2048*1182 =
// 2,420,736 = wf1 2,359,296 | w2p 51,200 | wf2p 10,240), then conv1+BN+sign+
// pool for its image, writing act1 in k2's padded+swizzled layout.
// Conv phase reads x DIRECT from global: 32 oc-lanes share a cell -> all 8
// float2 loads are L1 broadcasts. No LDS, no barriers.
__global__ __launch_bounds__(256) void k1_prep(
        const float* __restrict__ x,
        const float* __restrict__ w1, const float* __restrict__ b1,
        const float* __restrict__ g1, const float* __restrict__ be1,
        const float* __restrict__ m1, const float* __restrict__ v1,
        const float* __restrict__ w2, const float* __restrict__ wf1,
        const float* __restrict__ wf2,
        signed char* __restrict__ w2p, signed char* __restrict__ wf1s,
        signed char* __restrict__ wf2p, signed char* __restrict__ act1) {
    int b = blockIdx.x, tid = threadIdx.x;

    // ---- prep slice: 1182 elements, 5 strided iterations ----
    {
        int base = b * 1182;
        for (int t = tid; t < 1182; t += 256) {
            int i = base + t;
            if (i < 2359296) {                  // wf1 sign (natural layout)
                float v = wf1[i];
                wf1s[i] = v > 0.f ? 1 : (v < 0.f ? -1 : 0);
            } else if (i < 2359296 + 51200) {   // w2p [tap][half][oc][16]
                int ii = i - 2359296;
                int tap = ii >> 11;
                int r = ii & 2047;
                int half = r >> 10;
                int r2 = r & 1023;
                int oc = r2 >> 4, j = r2 & 15;
                int ic = half * 16 + j;
                float v = w2[(oc * 32 + ic) * 25 + tap];
                w2p[ii] = v > 0.f ? 1 : (v < 0.f ? -1 : 0);
            } else {                            // wf2 sign
                int ii = i - 2359296 - 51200;
                float v = wf2[ii];
                wf2p[ii] = v > 0.f ? 1 : (v < 0.f ? -1 : 0);
            }
        }
    }

    signed char* img = act1 + (size_t)b * 9248;
    // zero the 120 border pixels (240 x 16B chunks); disjoint from interior
    i32x4 z4 = {0, 0, 0, 0};
    for (int i = tid; i < 240; i += 256) {
        int pi = i >> 1, half = i & 1;
        int p;
        if (pi < 34) p = pi;                       // rows 0-1
        else if (pi < 68) p = 255 + (pi - 34);     // rows 15-16
        else {                                     // rows 2-14, cols 0,1,15,16
            int j2 = pi - 68;
            int row = 2 + (j2 >> 2), c = j2 & 3;
            int col = (c < 2) ? c : 13 + c;        // 0,1,15,16
            p = row * 17 + col;
        }
        *(i32x4*)(img + aswz(p * 32 + half * 16)) = z4;
    }

    // ---- conv1 + BN + sign + pool2 ----
    int oc = tid & 31, g = tid >> 5;
    float sw[9];
#pragma unroll
    for (int i = 0; i < 9; i++) sw[i] = fsign(w1[oc * 9 + i]);
    float bias = b1[oc], m = m1[oc];
    float sc = g1[oc] / sqrtf(v1[oc] + 1e-5f), bb = be1[oc];
    const float* xb = x + (size_t)b * 784;

    for (int i = 0; i < 22; i++) {
        int cell = i * 8 + g;
        if (cell < 169) {
            int py = cell / 13, px = cell - py * 13;
            const float* wnd = xb + py * 56 + px * 2;   // even offset: 8B aligned
            float xr[4][4];
#pragma unroll
            for (int dy = 0; dy < 4; dy++) {
                float2 lo = *(const float2*)(wnd + dy * 28);
                float2 hi = *(const float2*)(wnd + dy * 28 + 2);
                xr[dy][0] = lo.x; xr[dy][1] = lo.y;
                xr[dy][2] = hi.x; xr[dy][3] = hi.y;
            }
            float maxacc = -1e30f;
#pragma unroll
            for (int q = 0; q < 4; q++) {
                int dyp = q >> 1, dxp = q & 1;
                float acc = 0.f;
#pragma unroll
                for (int ky = 0; ky < 3; ky++)
#pragma unroll
                    for (int kx = 0; kx < 3; kx++)
                        acc += xr[dyp + ky][dxp + kx] * sw[ky * 3 + kx];
                maxacc = fmaxf(maxacc, acc);   // BN monotone (sc>0): max commutes
            }
            float bn = (maxacc + bias - m) * sc + bb;  // same assoc as before
            int p32 = ((py + 2) * 17 + (px + 2)) * 32;
            img[aswz(p32 + oc)] = (signed char)fsign(bn);
        }
    }
}

// K2: conv2 implicit-GEMM MFMA i8. Block = 8 images, 12 waves (768 thr).
// Grid = 256 = 1 block/CU. Staging = pure linear copy. (r20 verbatim)
#define K2_IMG_STRIDE 9248          // 17*17*32
#define K2_WOFF 73984               // 8*9248
__global__ __launch_bounds__(768) void k2_mfma(
        const signed char* __restrict__ act1, const signed char* __restrict__ w2p,
        const float* __restrict__ b2, const float* __restrict__ g2,
        const float* __restrict__ be2, const float* __restrict__ m2,
        const float* __restrict__ v2, signed char* __restrict__ act2) {
    __shared__ __align__(16) signed char smem[125184];
    int tid = threadIdx.x;
    int b0 = blockIdx.x * 8;

    {
        const i32x4* asrc = (const i32x4*)(act1 + (size_t)b0 * 9248);
        i32x4* s4 = (i32x4*)smem;
        for (int i = tid; i < 4624; i += 768) s4[i] = asrc[i];
        const i32x4* wsrc = (const i32x4*)w2p;
        i32x4* w4 = (i32x4*)(smem + K2_WOFF);
        for (int i = tid; i < 3200; i += 768) w4[i] = wsrc[i];
    }
    __syncthreads();

    int wave = tid >> 6, lane = tid & 63;
    int lrow = lane & 31, kh = lane >> 5;
    const signed char* wbase = smem + K2_WOFF + kh * 1024 + lrow * 16;

    const signed char* aimg[3];
    int pixbase[3];
#pragma unroll
    for (int t = 0; t < 3; ++t) {
        int mt = wave * 3 + t;                // 0..35
        int m = mt * 32 + lrow;
        int q = m >> 2, j = m & 3;
        int img = q / 36, qq = q - img * 36;
        int oy = 2 * (qq / 6) + (j >> 1);
        int ox = 2 * (qq - (qq / 6) * 6) + (j & 1);
        aimg[t] = smem + img * K2_IMG_STRIDE;
        pixbase[t] = oy * 17 + ox;
    }

    i32x16 acc[3][2] = {};
#pragma unroll 5
    for (int tap = 0; tap < 25; ++tap) {
        int ky = tap / 5, kx = tap - (tap / 5) * 5;
        i32x4 w0 = *(const i32x4*)(wbase + tap * 2048);        // oc = lrow
        i32x4 w1v = *(const i32x4*)(wbase + tap * 2048 + 512); // oc = 32+lrow
#pragma unroll
        for (int t = 0; t < 3; ++t) {
            int off = (pixbase[t] + ky * 17 + kx) * 32 + kh * 16;
            i32x4 a = *(const i32x4*)(aimg[t] + aswz(off));
            acc[t][0] = __builtin_amdgcn_mfma_i32_32x32x32_i8(a, w0, acc[t][0], 0, 0, 0);
            acc[t][1] = __builtin_amdgcn_mfma_i32_32x32x32_i8(a, w1v, acc[t][1], 0, 0, 0);
        }
    }
    __syncthreads();   // all LDS A/W reads done -> act region reusable

    float bi[2], mm2[2], sc2[2], bb2[2];
#pragma unroll
    for (int h = 0; h < 2; ++h) {
        int oc = h * 32 + lrow;
        bi[h] = b2[oc]; mm2[h] = m2[oc];
        sc2[h] = g2[oc] / sqrtf(v2[oc] + 1e-5f); bb2[h] = be2[oc];
    }
#pragma unroll
    for (int t = 0; t < 3; ++t) {
        int mt = wave * 3 + t;
#pragma unroll
        for (int h = 0; h < 2; ++h) {
            int oc = h * 32 + lrow;
#pragma unroll
            for (int g = 0; g < 4; g++) {
                int qo = mt * 8 + kh + 2 * g;     // pool cell 0..287 (8 images)
                int imo = qo / 36, qqo = qo - imo * 36;
                float best = -2.f;
#pragma unroll
                for (int jj = 0; jj < 4; jj++) {
                    float z = (float)acc[t][h][g * 4 + jj] + bi[h];
                    float bn = (z - mm2[h]) * sc2[h] + bb2[h];
                    best = fmaxf(best, fsign(bn));
                }
                smem[imo * 2304 + oc * 36 + qqo] = (signed char)best;
            }
        }
    }
    __syncthreads();
    {
        const i32x4* s4o = (const i32x4*)smem;
        i32x4* dst = (i32x4*)(act2 + (size_t)b0 * 2304);
        for (int i = tid; i < 1152; i += 768) dst[i] = s4o[i];
    }
}

// K3: fc1 as LDS-tiled MFMA i8 GEMM 2048x1024x2304. (r20 verbatim)
#define K3A_SEG 2064                // 128*16 + 16 pad
#define K3B_SEG 1040                // 64*16 + 16 pad
#define K3_BOFF 16512               // 8 * 2064
__global__ __launch_bounds__(256) void k3_mfma(
        const signed char* __restrict__ act2, const signed char* __restrict__ wf1s,
        const float* __restrict__ bf1, const float* __restrict__ gf1,
        const float* __restrict__ bef1, const float* __restrict__ mf1,
        const float* __restrict__ vf1, signed char* __restrict__ act3) {
    __shared__ __align__(16) signed char s[K3_BOFF + 8 * K3B_SEG];  // 24832
    int tid = threadIdx.x;
    int bid = blockIdx.x;
    int tn = bid & 15, tm = bid >> 4;

    const signed char* Ab = act2 + (size_t)tm * 128 * 2304;
    const signed char* Bb = wf1s + (size_t)tn * 64 * 2304;
    size_t gA[4]; int lwA[4];
#pragma unroll
    for (int i = 0; i < 4; i++) {
        int e = tid + 256 * i, row = e >> 3, sg = (e + row) & 7;
        gA[i] = (size_t)row * 2304 + sg * 16;
        lwA[i] = sg * K3A_SEG + row * 16;
    }
    size_t gB[2]; int lwB[2];
#pragma unroll
    for (int i = 0; i < 2; i++) {
        int e = tid + 256 * i, row = e >> 3, sg = (e + row) & 7;
        gB[i] = (size_t)row * 2304 + sg * 16;
        lwB[i] = K3_BOFF + sg * K3B_SEG + row * 16;
    }

    i32x4 ra[4], rb[2];
#pragma unroll
    for (int i = 0; i < 4; i++) ra[i] = *(const i32x4*)(Ab + gA[i]);
#pragma unroll
    for (int i = 0; i < 2; i++) rb[i] = *(const i32x4*)(Bb + gB[i]);

    int l = tid & 63, wid = tid >> 6;
    int lrow = l & 31, kh = l >> 5;
    int raddrA = kh * K3A_SEG + (wid * 32 + lrow) * 16;
    int raddrB0 = K3_BOFF + kh * K3B_SEG + lrow * 16;
    int raddrB1 = raddrB0 + 32 * 16;

    i32x16 acc0 = {0};
    i32x16 acc1 = {0};
    for (int t = 0; t < 18; ++t) {
        if (t) __syncthreads();
#pragma unroll
        for (int i = 0; i < 4; i++) *(i32x4*)(s + lwA[i]) = ra[i];
#pragma unroll
        for (int i = 0; i < 2; i++) *(i32x4*)(s + lwB[i]) = rb[i];
        if (t < 17) {
            size_t ko = (size_t)(t + 1) * 128;
#pragma unroll
            for (int i = 0; i < 4; i++) ra[i] = *(const i32x4*)(Ab + gA[i] + ko);
#pragma unroll
            for (int i = 0; i < 2; i++) rb[i] = *(const i32x4*)(Bb + gB[i] + ko);
        }
        __syncthreads();
#pragma unroll
        for (int ks = 0; ks < 4; ++ks) {
            i32x4 a  = *(const i32x4*)(s + raddrA + ks * 2 * K3A_SEG);
            i32x4 b0 = *(const i32x4*)(s + raddrB0 + ks * 2 * K3B_SEG);
            i32x4 b1 = *(const i32x4*)(s + raddrB1 + ks * 2 * K3B_SEG);
            acc0 = __builtin_amdgcn_mfma_i32_32x32x32_i8(a, b0, acc0, 0, 0, 0);
            acc1 = __builtin_amdgcn_mfma_i32_32x32x32_i8(a, b1, acc1, 0, 0, 0);
        }
    }

    int col0 = tn * 64 + lrow;
    int col1 = col0 + 32;
    float bi0 = bf1[col0], m0 = mf1[col0];
    float sc0 = gf1[col0] / sqrtf(vf1[col0] + 1e-5f), bb0 = bef1[col0];
    float bi1 = bf1[col1], m1 = mf1[col1];
    float sc1 = gf1[col1] / sqrtf(vf1[col1] + 1e-5f), bb1 = bef1[col1];
    __syncthreads();   // K-loop reads of s done -> reuse as output tile [128][64]
#pragma unroll
    for (int r = 0; r < 16; r++) {
        int rowl = wid * 32 + (r & 3) + 8 * (r >> 2) + 4 * kh;
        float bn0 = ((float)acc0[r] + bi0 - m0) * sc0 + bb0;
        float bn1 = ((float)acc1[r] + bi1 - m1) * sc1 + bb1;
        s[rowl * 64 + lrow] = (signed char)fsign(bn0);
        s[rowl * 64 + lrow + 32] = (signed char)fsign(bn1);
    }
    __syncthreads();
    for (int i = tid; i < 512; i += 256) {
        int rl = i >> 2, c16 = i & 3;
        *(i32x4*)(act3 + (size_t)(tm * 128 + rl) * 1024 + tn * 64 + c16 * 16) =
            *(const i32x4*)(s + i * 16);
    }
}

// K4: fc2 (1024->10) + bias + BN + log_softmax. One wave per image. (unchanged)
__global__ void k4_fc2(const signed char* __restrict__ act3, const signed char* __restrict__ swf2,
                       const float* __restrict__ bf2, const float* __restrict__ gf2,
                       const float* __restrict__ bef2, const float* __restrict__ mf2,
                       const float* __restrict__ vf2, float* __restrict__ out) {
    int wid = (blockIdx.x * 256 + threadIdx.x) >> 6;
    int lane = threadIdx.x & 63;
    if (wid >= BATCH) return;
    const int* hd = (const int*)act3 + (size_t)wid * 256;
    const int* wd = (const int*)swf2;
    int acc[10];
#pragma unroll
    for (int o = 0; o < 10; o++) acc[o] = 0;
#pragma unroll
    for (int i = 0; i < 4; i++) {
        int k4 = i * 64 + lane;
        int hv = hd[k4];
#pragma unroll
        for (int o = 0; o < 10; o++)
            acc[o] = sdot4(hv, wd[o * 256 + k4], acc[o]);
    }
#pragma unroll
    for (int o = 0; o < 10; o++)
#pragma unroll
        for (int s = 32; s > 0; s >>= 1) acc[o] += __shfl_xor(acc[o], s);
    if (lane == 0) {
        float logit[10];
        float mx = -1e30f;
#pragma unroll
        for (int o = 0; o < 10; o++) {
            float z = (float)acc[o] + bf2[o];
            float bn = (z - mf2[o]) * (gf2[o] / sqrtf(vf2[o] + 1e-5f)) + bef2[o];
            logit[o] = bn;
            mx = fmaxf(mx, bn);
        }
        float s = 0.f;
#pragma unroll
        for (int o = 0; o < 10; o++) s += expf(logit[o] - mx);
        float lse = mx + logf(s);
#pragma unroll
        for (int o = 0; o < 10; o++) out[(size_t)wid * 10 + o] = logit[o] - lse;
    }
}

extern "C" void kernel_launch(void* const* d_in, const int* in_sizes, int n_in,
                              void* d_out, int out_size, void* d_ws, size_t ws_size,
                              hipStream_t stream) {
    const float* x   = (const float*)d_in[0];
    const float* w1  = (const float*)d_in[1];
    const float* b1  = (const float*)d_in[2];
    const float* g1  = (const float*)d_in[3];
    const float* be1 = (const float*)d_in[4];
    const float* m1  = (const float*)d_in[5];
    const float* v1  = (const float*)d_in[6];
    const float* w2  = (const float*)d_in[7];
    const float* b2  = (const float*)d_in[8];
    const float* g2  = (const float*)d_in[9];
    const float* be2 = (const float*)d_in[10];
    const float* m2  = (const float*)d_in[11];
    const float* v2  = (const float*)d_in[12];
    const float* wf1 = (const float*)d_in[13];
    const float* bf1 = (const float*)d_in[14];
    const float* gf1 = (const float*)d_in[15];
    const float* bef1= (const float*)d_in[16];
    const float* mf1 = (const float*)d_in[17];
    const float* vf1 = (const float*)d_in[18];
    const float* wf2 = (const float*)d_in[19];
    const float* bf2 = (const float*)d_in[20];
    const float* gf2 = (const float*)d_in[21];
    const float* bef2= (const float*)d_in[22];
    const float* mf2 = (const float*)d_in[23];
    const float* vf2 = (const float*)d_in[24];
    float* out = (float*)d_out;

    // ws layout (all int8)
    char* ws = (char*)d_ws;
    signed char* act1 = (signed char*)ws;                  // 2048*9248     = 18,939,904
    signed char* act2 = act1 + 18939904;                   // 2048*2304     =  4,718,592
    signed char* act3 = act2 + 4718592;                    // 2048*1024     =  2,097,152
    signed char* w2p  = act3 + 2097152;                    // 25*2*64*16    =     51,200
    signed char* wf1s = w2p + 51200;                       // 1024*2304     =  2,359,296
    signed char* wf2p = wf1s + 2359296;                    // 10*1024       =     10,240

    k1_prep<<<2048, 256, 0, stream>>>(x, w1, b1, g1, be1, m1, v1, w2, wf1, wf2,
                                      w2p, wf1s, wf2p, act1);

    k2_mfma<<<256, 768, 0, stream>>>(act1, w2p, b2, g2, be2, m2, v2, act2);

    k3_mfma<<<256, 256, 0, stream>>>(act2, wf1s, bf1, gf1, bef1, mf1, vf1, act3);

    k4_fc2<<<512, 256, 0, stream>>>(act3, wf2p, bf2, gf2, bef2, mf2, vf2, out);
}

// Round 24
// 70.928 us; speedup vs baseline: 1.3651x; 1.0379x over previous
//
#include <hip/hip_runtime.h>
#include <math.h>

#define BATCH 2048

typedef __attribute__((ext_vector_type(4))) int i32x4;
typedef __attribute__((ext_vector_type(16))) int i32x16;
typedef __attribute__((ext_vector_type(2))) float f32x2;

__device__ __forceinline__ int sdot4(int a, int b, int c) {
    return __builtin_amdgcn_sdot4(a, b, c, false);
}

__device__ __forceinline__ float fsign(float v) {
    return v > 0.f ? 1.f : (v < 0.f ? -1.f : 0.f);
}

// act swizzle (T2): flips addr bits 4-6 by pixel bits 2-4; bijective on [0,9248),
// keeps 16B chunks intact, independent of the low 5 bits (oc).
__device__ __forceinline__ int aswz(int off) {
    return off ^ (((off >> 7) & 7) << 4);
}

// K1 + prep fused. Conv1 inner loop uses packed v_pk_fma_f32: the two dxp
// windows of each dyp half run as one f32x2 chain (18 pk-FMA vs 36 FMA).
// Per-lane accumulation order and fma contraction identical to the scalar
// version -> bit-identical results.
__global__ __launch_bounds__(256) void k1_prep(
        const float* __restrict__ x,
        const float* __restrict__ w1, const float* __restrict__ b1,
        const float* __restrict__ g1, const float* __restrict__ be1,
        const float* __restrict__ m1, const float* __restrict__ v1,
        const float* __restrict__ w2, const float* __restrict__ wf1,
        const float* __restrict__ wf2,
        signed char* __restrict__ w2p, signed char* __restrict__ wf1s,
        signed char* __restrict__ wf2p, signed char* __restrict__ act1) {
    int b = blockIdx.x, tid = threadIdx.x;

    // ---- prep slice: 1182 elements, 5 strided iterations ----
    {
        int base = b * 1182;
        for (int t = tid; t < 1182; t += 256) {
            int i = base + t;
            if (i < 2359296) {                  // wf1 sign (natural layout)
                float v = wf1[i];
                wf1s[i] = v > 0.f ? 1 : (v < 0.f ? -1 : 0);
            } else if (i < 2359296 + 51200) {   // w2p [tap][half][oc][16]
                int ii = i - 2359296;
                int tap = ii >> 11;
                int r = ii & 2047;
                int half = r >> 10;
                int r2 = r & 1023;
                int oc = r2 >> 4, j = r2 & 15;
                int ic = half * 16 + j;
                float v = w2[(oc * 32 + ic) * 25 + tap];
                w2p[ii] = v > 0.f ? 1 : (v < 0.f ? -1 : 0);
            } else {                            // wf2 sign
                int ii = i - 2359296 - 51200;
                float v = wf2[ii];
                wf2p[ii] = v > 0.f ? 1 : (v < 0.f ? -1 : 0);
            }
        }
    }

    signed char* img = act1 + (size_t)b * 9248;
    // zero the 120 border pixels (240 x 16B chunks); disjoint from interior
    i32x4 z4 = {0, 0, 0, 0};
    for (int i = tid; i < 240; i += 256) {
        int pi = i >> 1, half = i & 1;
        int p;
        if (pi < 34) p = pi;                       // rows 0-1
        else if (pi < 68) p = 255 + (pi - 34);     // rows 15-16
        else {                                     // rows 2-14, cols 0,1,15,16
            int j2 = pi - 68;
            int row = 2 + (j2 >> 2), c = j2 & 3;
            int col = (c < 2) ? c : 13 + c;        // 0,1,15,16
            p = row * 17 + col;
        }
        *(i32x4*)(img + aswz(p * 32 + half * 16)) = z4;
    }

    // ---- conv1 + BN + sign + pool2 (packed-FMA) ----
    int oc = tid & 31, g = tid >> 5;
    float sw[9];
#pragma unroll
    for (int i = 0; i < 9; i++) sw[i] = fsign(w1[oc * 9 + i]);
    float bias = b1[oc], m = m1[oc];
    float sc = g1[oc] / sqrtf(v1[oc] + 1e-5f), bb = be1[oc];
    const float* xb = x + (size_t)b * 784;

    for (int i = 0; i < 22; i++) {
        int cell = i * 8 + g;
        if (cell < 169) {
            int py = cell / 13, px = cell - py * 13;
            const float* wnd = xb + py * 56 + px * 2;   // even offset: 8B aligned
            f32x2 lo[4], hi[4], pm[4];
#pragma unroll
            for (int dy = 0; dy < 4; dy++) {
                lo[dy] = *(const f32x2*)(wnd + dy * 28);      // cols 0,1
                hi[dy] = *(const f32x2*)(wnd + dy * 28 + 2);  // cols 2,3
                pm[dy].x = lo[dy].y;                          // cols 1,2
                pm[dy].y = hi[dy].x;
            }
            // chains: lane0 = window dxp=0, lane1 = dxp=1; taps in original order
            f32x2 a01 = {0.f, 0.f};   // dyp = 0 (rows 0..2)
            f32x2 a23 = {0.f, 0.f};   // dyp = 1 (rows 1..3)
#pragma unroll
            for (int ky = 0; ky < 3; ky++) {
                a01 += lo[ky] * sw[ky * 3 + 0];
                a01 += pm[ky] * sw[ky * 3 + 1];
                a01 += hi[ky] * sw[ky * 3 + 2];
                a23 += lo[ky + 1] * sw[ky * 3 + 0];
                a23 += pm[ky + 1] * sw[ky * 3 + 1];
                a23 += hi[ky + 1] * sw[ky * 3 + 2];
            }
            // fmax is exact/assoc/comm: same result as original 4-term chain
            float maxacc = fmaxf(fmaxf(a01.x, a01.y), fmaxf(a23.x, a23.y));
            float bn = (maxacc + bias - m) * sc + bb;  // same assoc as before
            int p32 = ((py + 2) * 17 + (px + 2)) * 32;
            img[aswz(p32 + oc)] = (signed char)fsign(bn);
        }
    }
}

// K2: conv2 implicit-GEMM MFMA i8. Block = 8 images, 12 waves (768 thr).
// Grid = 256 = 1 block/CU. Staging = pure linear copy. (r23 verbatim)
#define K2_IMG_STRIDE 9248          // 17*17*32
#define K2_WOFF 73984               // 8*9248
__global__ __launch_bounds__(768) void k2_mfma(
        const signed char* __restrict__ act1, const signed char* __restrict__ w2p,
        const float* __restrict__ b2, const float* __restrict__ g2,
        const float* __restrict__ be2, const float* __restrict__ m2,
        const float* __restrict__ v2, signed char* __restrict__ act2) {
    __shared__ __align__(16) signed char smem[125184];
    int tid = threadIdx.x;
    int b0 = blockIdx.x * 8;

    {
        const i32x4* asrc = (const i32x4*)(act1 + (size_t)b0 * 9248);
        i32x4* s4 = (i32x4*)smem;
        for (int i = tid; i < 4624; i += 768) s4[i] = asrc[i];
        const i32x4* wsrc = (const i32x4*)w2p;
        i32x4* w4 = (i32x4*)(smem + K2_WOFF);
        for (int i = tid; i < 3200; i += 768) w4[i] = wsrc[i];
    }
    __syncthreads();

    int wave = tid >> 6, lane = tid & 63;
    int lrow = lane & 31, kh = lane >> 5;
    const signed char* wbase = smem + K2_WOFF + kh * 1024 + lrow * 16;

    const signed char* aimg[3];
    int pixbase[3];
#pragma unroll
    for (int t = 0; t < 3; ++t) {
        int mt = wave * 3 + t;                // 0..35
        int m = mt * 32 + lrow;
        int q = m >> 2, j = m & 3;
        int img = q / 36, qq = q - img * 36;
        int oy = 2 * (qq / 6) + (j >> 1);
        int ox = 2 * (qq - (qq / 6) * 6) + (j & 1);
        aimg[t] = smem + img * K2_IMG_STRIDE;
        pixbase[t] = oy * 17 + ox;
    }

    i32x16 acc[3][2] = {};
#pragma unroll 5
    for (int tap = 0; tap < 25; ++tap) {
        int ky = tap / 5, kx = tap - (tap / 5) * 5;
        i32x4 w0 = *(const i32x4*)(wbase + tap * 2048);        // oc = lrow
        i32x4 w1v = *(const i32x4*)(wbase + tap * 2048 + 512); // oc = 32+lrow
#pragma unroll
        for (int t = 0; t < 3; ++t) {
            int off = (pixbase[t] + ky * 17 + kx) * 32 + kh * 16;
            i32x4 a = *(const i32x4*)(aimg[t] + aswz(off));
            acc[t][0] = __builtin_amdgcn_mfma_i32_32x32x32_i8(a, w0, acc[t][0], 0, 0, 0);
            acc[t][1] = __builtin_amdgcn_mfma_i32_32x32x32_i8(a, w1v, acc[t][1], 0, 0, 0);
        }
    }
    __syncthreads();   // all LDS A/W reads done -> act region reusable

    float bi[2], mm2[2], sc2[2], bb2[2];
#pragma unroll
    for (int h = 0; h < 2; ++h) {
        int oc = h * 32 + lrow;
        bi[h] = b2[oc]; mm2[h] = m2[oc];
        sc2[h] = g2[oc] / sqrtf(v2[oc] + 1e-5f); bb2[h] = be2[oc];
    }
#pragma unroll
    for (int t = 0; t < 3; ++t) {
        int mt = wave * 3 + t;
#pragma unroll
        for (int h = 0; h < 2; ++h) {
            int oc = h * 32 + lrow;
#pragma unroll
            for (int g = 0; g < 4; g++) {
                int qo = mt * 8 + kh + 2 * g;     // pool cell 0..287 (8 images)
                int imo = qo / 36, qqo = qo - imo * 36;
                float best = -2.f;
#pragma unroll
                for (int jj = 0; jj < 4; jj++) {
                    float z = (float)acc[t][h][g * 4 + jj] + bi[h];
                    float bn = (z - mm2[h]) * sc2[h] + bb2[h];
                    best = fmaxf(best, fsign(bn));
                }
                smem[imo * 2304 + oc * 36 + qqo] = (signed char)best;
            }
        }
    }
    __syncthreads();
    {
        const i32x4* s4o = (const i32x4*)smem;
        i32x4* dst = (i32x4*)(act2 + (size_t)b0 * 2304);
        for (int i = tid; i < 1152; i += 768) dst[i] = s4o[i];
    }
}

// K3: fc1 as LDS-tiled MFMA i8 GEMM 2048x1024x2304. (r23 verbatim)
#define K3A_SEG 2064                // 128*16 + 16 pad
#define K3B_SEG 1040                // 64*16 + 16 pad
#define K3_BOFF 16512               // 8 * 2064
__global__ __launch_bounds__(256) void k3_mfma(
        const signed char* __restrict__ act2, const signed char* __restrict__ wf1s,
        const float* __restrict__ bf1, const float* __restrict__ gf1,
        const float* __restrict__ bef1, const float* __restrict__ mf1,
        const float* __restrict__ vf1, signed char* __restrict__ act3) {
    __shared__ __align__(16) signed char s[K3_BOFF + 8 * K3B_SEG];  // 24832
    int tid = threadIdx.x;
    int bid = blockIdx.x;
    int tn = bid & 15, tm = bid >> 4;

    const signed char* Ab = act2 + (size_t)tm * 128 * 2304;
    const signed char* Bb = wf1s + (size_t)tn * 64 * 2304;
    size_t gA[4]; int lwA[4];
#pragma unroll
    for (int i = 0; i < 4; i++) {
        int e = tid + 256 * i, row = e >> 3, sg = (e + row) & 7;
        gA[i] = (size_t)row * 2304 + sg * 16;
        lwA[i] = sg * K3A_SEG + row * 16;
    }
    size_t gB[2]; int lwB[2];
#pragma unroll
    for (int i = 0; i < 2; i++) {
        int e = tid + 256 * i, row = e >> 3, sg = (e + row) & 7;
        gB[i] = (size_t)row * 2304 + sg * 16;
        lwB[i] = K3_BOFF + sg * K3B_SEG + row * 16;
    }

    i32x4 ra[4], rb[2];
#pragma unroll
    for (int i = 0; i < 4; i++) ra[i] = *(const i32x4*)(Ab + gA[i]);
#pragma unroll
    for (int i = 0; i < 2; i++) rb[i] = *(const i32x4*)(Bb + gB[i]);

    int l = tid & 63, wid = tid >> 6;
    int lrow = l & 31, kh = l >> 5;
    int raddrA = kh * K3A_SEG + (wid * 32 + lrow) * 16;
    int raddrB0 = K3_BOFF + kh * K3B_SEG + lrow * 16;
    int raddrB1 = raddrB0 + 32 * 16;

    i32x16 acc0 = {0};
    i32x16 acc1 = {0};
    for (int t = 0; t < 18; ++t) {
        if (t) __syncthreads();
#pragma unroll
        for (int i = 0; i < 4; i++) *(i32x4*)(s + lwA[i]) = ra[i];
#pragma unroll
        for (int i = 0; i < 2; i++) *(i32x4*)(s + lwB[i]) = rb[i];
        if (t < 17) {
            size_t ko = (size_t)(t + 1) * 128;
#pragma unroll
            for (int i = 0; i < 4; i++) ra[i] = *(const i32x4*)(Ab + gA[i] + ko);
#pragma unroll
            for (int i = 0; i < 2; i++) rb[i] = *(const i32x4*)(Bb + gB[i] + ko);
        }
        __syncthreads();
#pragma unroll
        for (int ks = 0; ks < 4; ++ks) {
            i32x4 a  = *(const i32x4*)(s + raddrA + ks * 2 * K3A_SEG);
            i32x4 b0 = *(const i32x4*)(s + raddrB0 + ks * 2 * K3B_SEG);
            i32x4 b1 = *(const i32x4*)(s + raddrB1 + ks * 2 * K3B_SEG);
            acc0 = __builtin_amdgcn_mfma_i32_32x32x32_i8(a, b0, acc0, 0, 0, 0);
            acc1 = __builtin_amdgcn_mfma_i32_32x32x32_i8(a, b1, acc1, 0, 0, 0);
        }
    }

    int col0 = tn * 64 + lrow;
    int col1 = col0 + 32;
    float bi0 = bf1[col0], m0 = mf1[col0];
    float sc0 = gf1[col0] / sqrtf(vf1[col0] + 1e-5f), bb0 = bef1[col0];
    float bi1 = bf1[col1], m1 = mf1[col1];
    float sc1 = gf1[col1] / sqrtf(vf1[col1] + 1e-5f), bb1 = bef1[col1];
    __syncthreads();   // K-loop reads of s done -> reuse as output tile [128][64]
#pragma unroll
    for (int r = 0; r < 16; r++) {
        int rowl = wid * 32 + (r & 3) + 8 * (r >> 2) + 4 * kh;
        float bn0 = ((float)acc0[r] + bi0 - m0) * sc0 + bb0;
        float bn1 = ((float)acc1[r] + bi1 - m1) * sc1 + bb1;
        s[rowl * 64 + lrow] = (signed char)fsign(bn0);
        s[rowl * 64 + lrow + 32] = (signed char)fsign(bn1);
    }
    __syncthreads();
    for (int i = tid; i < 512; i += 256) {
        int rl = i >> 2, c16 = i & 3;
        *(i32x4*)(act3 + (size_t)(tm * 128 + rl) * 1024 + tn * 64 + c16 * 16) =
            *(const i32x4*)(s + i * 16);
    }
}

// K4: fc2 (1024->10) + bias + BN + log_softmax. One wave per image. (unchanged)
__global__ void k4_fc2(const signed char* __restrict__ act3, const signed char* __restrict__ swf2,
                       const float* __restrict__ bf2, const float* __restrict__ gf2,
                       const float* __restrict__ bef2, const float* __restrict__ mf2,
                       const float* __restrict__ vf2, float* __restrict__ out) {
    int wid = (blockIdx.x * 256 + threadIdx.x) >> 6;
    int lane = threadIdx.x & 63;
    if (wid >= BATCH) return;
    const int* hd = (const int*)act3 + (size_t)wid * 256;
    const int* wd = (const int*)swf2;
    int acc[10];
#pragma unroll
    for (int o = 0; o < 10; o++) acc[o] = 0;
#pragma unroll
    for (int i = 0; i < 4; i++) {
        int k4 = i * 64 + lane;
        int hv = hd[k4];
#pragma unroll
        for (int o = 0; o < 10; o++)
            acc[o] = sdot4(hv, wd[o * 256 + k4], acc[o]);
    }
#pragma unroll
    for (int o = 0; o < 10; o++)
#pragma unroll
        for (int s = 32; s > 0; s >>= 1) acc[o] += __shfl_xor(acc[o], s);
    if (lane == 0) {
        float logit[10];
        float mx = -1e30f;
#pragma unroll
        for (int o = 0; o < 10; o++) {
            float z = (float)acc[o] + bf2[o];
            float bn = (z - mf2[o]) * (gf2[o] / sqrtf(vf2[o] + 1e-5f)) + bef2[o];
            logit[o] = bn;
            mx = fmaxf(mx, bn);
        }
        float s = 0.f;
#pragma unroll
        for (int o = 0; o < 10; o++) s += expf(logit[o] - mx);
        float lse = mx + logf(s);
#pragma unroll
        for (int o = 0; o < 10; o++) out[(size_t)wid * 10 + o] = logit[o] - lse;
    }
}

extern "C" void kernel_launch(void* const* d_in, const int* in_sizes, int n_in,
                              void* d_out, int out_size, void* d_ws, size_t ws_size,
                              hipStream_t stream) {
    const float* x   = (const float*)d_in[0];
    const float* w1  = (const float*)d_in[1];
    const float* b1  = (const float*)d_in[2];
    const float* g1  = (const float*)d_in[3];
    const float* be1 = (const float*)d_in[4];
    const float* m1  = (const float*)d_in[5];
    const float* v1  = (const float*)d_in[6];
    const float* w2  = (const float*)d_in[7];
    const float* b2  = (const float*)d_in[8];
    const float* g2  = (const float*)d_in[9];
    const float* be2 = (const float*)d_in[10];
    const float* m2  = (const float*)d_in[11];
    const float* v2  = (const float*)d_in[12];
    const float* wf1 = (const float*)d_in[13];
    const float* bf1 = (const float*)d_in[14];
    const float* gf1 = (const float*)d_in[15];
    const float* bef1= (const float*)d_in[16];
    const float* mf1 = (const float*)d_in[17];
    const float* vf1 = (const float*)d_in[18];
    const float* wf2 = (const float*)d_in[19];
    const float* bf2 = (const float*)d_in[20];
    const float* gf2 = (const float*)d_in[21];
    const float* bef2= (const float*)d_in[22];
    const float* mf2 = (const float*)d_in[23];
    const float* vf2 = (const float*)d_in[24];
    float* out = (float*)d_out;

    // ws layout (all int8)
    char* ws = (char*)d_ws;
    signed char* act1 = (signed char*)ws;                  // 2048*9248     = 18,939,904
    signed char* act2 = act1 + 18939904;                   // 2048*2304     =  4,718,592
    signed char* act3 = act2 + 4718592;                    // 2048*1024     =  2,097,152
    signed char* w2p  = act3 + 2097152;                    // 25*2*64*16    =     51,200
    signed char* wf1s = w2p + 51200;                       // 1024*2304     =  2,359,296
    signed char* wf2p = wf1s + 2359296;                    // 10*1024       =     10,240

    k1_prep<<<2048, 256, 0, stream>>>(x, w1, b1, g1, be1, m1, v1, w2, wf1, wf2,
                                      w2p, wf1s, wf2p, act1);

    k2_mfma<<<256, 768, 0, stream>>>(act1, w2p, b2, g2, be2, m2, v2, act2);

    k3_mfma<<<256, 256, 0, stream>>>(act2, wf1s, bf1, gf1, bef1, mf1, vf1, act3);

    k4_fc2<<<512, 256, 0, stream>>>(act3, wf2p, bf2, gf2, bef2, mf2, vf2, out);
}

// Round 25
// 65.861 us; speedup vs baseline: 1.4701x; 1.0769x over previous
//
#include <hip/hip_runtime.h>
#include <math.h>

#define BATCH 2048

typedef __attribute__((ext_vector_type(4))) int i32x4;
typedef __attribute__((ext_vector_type(16))) int i32x16;
typedef __attribute__((ext_vector_type(2))) float f32x2;

__device__ __forceinline__ int sdot4(int a, int b, int c) {
    return __builtin_amdgcn_sdot4(a, b, c, false);
}

__device__ __forceinline__ float fsign(float v) {
    return v > 0.f ? 1.f : (v < 0.f ? -1.f : 0.f);
}

// act swizzle (T2): flips addr bits 4-6 by pixel bits 2-4; bijective on [0,9248),
// keeps 16B chunks intact, independent of the low 5 bits (oc).
__device__ __forceinline__ int aswz(int off) {
    return off ^ (((off >> 7) & 7) << 4);
}

// K1 + prep fused. Conv1: thread = (oc, pool-row py); px walks 0..12 with a
// fully-unrolled sliding window (lo<-hi register rotation, 4 new loads/cell,
// immediate-offset addressing). pk-FMA chains identical to r24 -> bit-identical.
__global__ __launch_bounds__(256) void k1_prep(
        const float* __restrict__ x,
        const float* __restrict__ w1, const float* __restrict__ b1,
        const float* __restrict__ g1, const float* __restrict__ be1,
        const float* __restrict__ m1, const float* __restrict__ v1,
        const float* __restrict__ w2, const float* __restrict__ wf1,
        const float* __restrict__ wf2,
        signed char* __restrict__ w2p, signed char* __restrict__ wf1s,
        signed char* __restrict__ wf2p, signed char* __restrict__ act1) {
    int b = blockIdx.x, tid = threadIdx.x;

    // ---- prep slice: 1182 elements, 5 strided iterations ----
    {
        int base = b * 1182;
        for (int t = tid; t < 1182; t += 256) {
            int i = base + t;
            if (i < 2359296) {                  // wf1 sign (natural layout)
                float v = wf1[i];
                wf1s[i] = v > 0.f ? 1 : (v < 0.f ? -1 : 0);
            } else if (i < 2359296 + 51200) {   // w2p [tap][half][oc][16]
                int ii = i - 2359296;
                int tap = ii >> 11;
                int r = ii & 2047;
                int half = r >> 10;
                int r2 = r & 1023;
                int oc = r2 >> 4, j = r2 & 15;
                int ic = half * 16 + j;
                float v = w2[(oc * 32 + ic) * 25 + tap];
                w2p[ii] = v > 0.f ? 1 : (v < 0.f ? -1 : 0);
            } else {                            // wf2 sign
                int ii = i - 2359296 - 51200;
                float v = wf2[ii];
                wf2p[ii] = v > 0.f ? 1 : (v < 0.f ? -1 : 0);
            }
        }
    }

    signed char* img = act1 + (size_t)b * 9248;
    // zero the 120 border pixels (240 x 16B chunks); disjoint from interior
    i32x4 z4 = {0, 0, 0, 0};
    for (int i = tid; i < 240; i += 256) {
        int pi = i >> 1, half = i & 1;
        int p;
        if (pi < 34) p = pi;                       // rows 0-1
        else if (pi < 68) p = 255 + (pi - 34);     // rows 15-16
        else {                                     // rows 2-14, cols 0,1,15,16
            int j2 = pi - 68;
            int row = 2 + (j2 >> 2), c = j2 & 3;
            int col = (c < 2) ? c : 13 + c;        // 0,1,15,16
            p = row * 17 + col;
        }
        *(i32x4*)(img + aswz(p * 32 + half * 16)) = z4;
    }

    // ---- conv1 + BN + sign + pool2 (sliding-window, packed-FMA) ----
    int oc = tid & 31, g = tid >> 5;
    float sw[9];
#pragma unroll
    for (int i = 0; i < 9; i++) sw[i] = fsign(w1[oc * 9 + i]);
    float bias = b1[oc], m = m1[oc];
    float sc = g1[oc] / sqrtf(v1[oc] + 1e-5f), bb = be1[oc];
    const float* xb = x + (size_t)b * 784;

#pragma unroll
    for (int rep = 0; rep < 2; rep++) {
        int py = g + 8 * rep;
        if (py < 13) {
            const float* rowp = xb + py * 56;     // conv row 2py
            int p32base = ((py + 2) * 17 + 2) * 32;
            f32x2 lo[4], hi[4];
#pragma unroll
            for (int dy = 0; dy < 4; dy++) {
                lo[dy] = *(const f32x2*)(rowp + dy * 28);      // cols 0,1
                hi[dy] = *(const f32x2*)(rowp + dy * 28 + 2);  // cols 2,3
            }
#pragma unroll
            for (int px = 0; px < 13; px++) {
                f32x2 pm[4];
#pragma unroll
                for (int dy = 0; dy < 4; dy++) {
                    pm[dy].x = lo[dy].y;          // cols 2px+1, 2px+2
                    pm[dy].y = hi[dy].x;
                }
                f32x2 a01 = {0.f, 0.f};   // dyp = 0 (rows 0..2)
                f32x2 a23 = {0.f, 0.f};   // dyp = 1 (rows 1..3)
#pragma unroll
                for (int ky = 0; ky < 3; ky++) {
                    a01 += lo[ky] * sw[ky * 3 + 0];
                    a01 += pm[ky] * sw[ky * 3 + 1];
                    a01 += hi[ky] * sw[ky * 3 + 2];
                    a23 += lo[ky + 1] * sw[ky * 3 + 0];
                    a23 += pm[ky + 1] * sw[ky * 3 + 1];
                    a23 += hi[ky + 1] * sw[ky * 3 + 2];
                }
                float maxacc = fmaxf(fmaxf(a01.x, a01.y), fmaxf(a23.x, a23.y));
                float bn = (maxacc + bias - m) * sc + bb;  // same assoc as r24
                img[aswz(p32base + px * 32 + oc)] = (signed char)fsign(bn);
                if (px < 12) {
#pragma unroll
                    for (int dy = 0; dy < 4; dy++) {
                        lo[dy] = hi[dy];          // rotation: no loads re-done
                        hi[dy] = *(const f32x2*)(rowp + dy * 28 + 2 * px + 4);
                    }
                }
            }
        }
    }
}

// K2: conv2 implicit-GEMM MFMA i8. Block = 8 images, 12 waves (768 thr).
// Grid = 256 = 1 block/CU. Staging = pure linear copy. (r24 verbatim)
#define K2_IMG_STRIDE 9248          // 17*17*32
#define K2_WOFF 73984               // 8*9248
__global__ __launch_bounds__(768) void k2_mfma(
        const signed char* __restrict__ act1, const signed char* __restrict__ w2p,
        const float* __restrict__ b2, const float* __restrict__ g2,
        const float* __restrict__ be2, const float* __restrict__ m2,
        const float* __restrict__ v2, signed char* __restrict__ act2) {
    __shared__ __align__(16) signed char smem[125184];
    int tid = threadIdx.x;
    int b0 = blockIdx.x * 8;

    {
        const i32x4* asrc = (const i32x4*)(act1 + (size_t)b0 * 9248);
        i32x4* s4 = (i32x4*)smem;
        for (int i = tid; i < 4624; i += 768) s4[i] = asrc[i];
        const i32x4* wsrc = (const i32x4*)w2p;
        i32x4* w4 = (i32x4*)(smem + K2_WOFF);
        for (int i = tid; i < 3200; i += 768) w4[i] = wsrc[i];
    }
    __syncthreads();

    int wave = tid >> 6, lane = tid & 63;
    int lrow = lane & 31, kh = lane >> 5;
    const signed char* wbase = smem + K2_WOFF + kh * 1024 + lrow * 16;

    const signed char* aimg[3];
    int pixbase[3];
#pragma unroll
    for (int t = 0; t < 3; ++t) {
        int mt = wave * 3 + t;                // 0..35
        int m = mt * 32 + lrow;
        int q = m >> 2, j = m & 3;
        int img = q / 36, qq = q - img * 36;
        int oy = 2 * (qq / 6) + (j >> 1);
        int ox = 2 * (qq - (qq / 6) * 6) + (j & 1);
        aimg[t] = smem + img * K2_IMG_STRIDE;
        pixbase[t] = oy * 17 + ox;
    }

    i32x16 acc[3][2] = {};
#pragma unroll 5
    for (int tap = 0; tap < 25; ++tap) {
        int ky = tap / 5, kx = tap - (tap / 5) * 5;
        i32x4 w0 = *(const i32x4*)(wbase + tap * 2048);        // oc = lrow
        i32x4 w1v = *(const i32x4*)(wbase + tap * 2048 + 512); // oc = 32+lrow
#pragma unroll
        for (int t = 0; t < 3; ++t) {
            int off = (pixbase[t] + ky * 17 + kx) * 32 + kh * 16;
            i32x4 a = *(const i32x4*)(aimg[t] + aswz(off));
            acc[t][0] = __builtin_amdgcn_mfma_i32_32x32x32_i8(a, w0, acc[t][0], 0, 0, 0);
            acc[t][1] = __builtin_amdgcn_mfma_i32_32x32x32_i8(a, w1v, acc[t][1], 0, 0, 0);
        }
    }
    __syncthreads();   // all LDS A/W reads done -> act region reusable

    float bi[2], mm2[2], sc2[2], bb2[2];
#pragma unroll
    for (int h = 0; h < 2; ++h) {
        int oc = h * 32 + lrow;
        bi[h] = b2[oc]; mm2[h] = m2[oc];
        sc2[h] = g2[oc] / sqrtf(v2[oc] + 1e-5f); bb2[h] = be2[oc];
    }
#pragma unroll
    for (int t = 0; t < 3; ++t) {
        int mt = wave * 3 + t;
#pragma unroll
        for (int h = 0; h < 2; ++h) {
            int oc = h * 32 + lrow;
#pragma unroll
            for (int g = 0; g < 4; g++) {
                int qo = mt * 8 + kh + 2 * g;     // pool cell 0..287 (8 images)
                int imo = qo / 36, qqo = qo - imo * 36;
                float best = -2.f;
#pragma unroll
                for (int jj = 0; jj < 4; jj++) {
                    float z = (float)acc[t][h][g * 4 + jj] + bi[h];
                    float bn = (z - mm2[h]) * sc2[h] + bb2[h];
                    best = fmaxf(best, fsign(bn));
                }
                smem[imo * 2304 + oc * 36 + qqo] = (signed char)best;
            }
        }
    }
    __syncthreads();
    {
        const i32x4* s4o = (const i32x4*)smem;
        i32x4* dst = (i32x4*)(act2 + (size_t)b0 * 2304);
        for (int i = tid; i < 1152; i += 768) dst[i] = s4o[i];
    }
}

// K3: fc1 as LDS-tiled MFMA i8 GEMM 2048x1024x2304. (r24 verbatim)
#define K3A_SEG 2064                // 128*16 + 16 pad
#define K3B_SEG 1040                // 64*16 + 16 pad
#define K3_BOFF 16512               // 8 * 2064
__global__ __launch_bounds__(256) void k3_mfma(
        const signed char* __restrict__ act2, const signed char* __restrict__ wf1s,
        const float* __restrict__ bf1, const float* __restrict__ gf1,
        const float* __restrict__ bef1, const float* __restrict__ mf1,
        const float* __restrict__ vf1, signed char* __restrict__ act3) {
    __shared__ __align__(16) signed char s[K3_BOFF + 8 * K3B_SEG];  // 24832
    int tid = threadIdx.x;
    int bid = blockIdx.x;
    int tn = bid & 15, tm = bid >> 4;

    const signed char* Ab = act2 + (size_t)tm * 128 * 2304;
    const signed char* Bb = wf1s + (size_t)tn * 64 * 2304;
    size_t gA[4]; int lwA[4];
#pragma unroll
    for (int i = 0; i < 4; i++) {
        int e = tid + 256 * i, row = e >> 3, sg = (e + row) & 7;
        gA[i] = (size_t)row * 2304 + sg * 16;
        lwA[i] = sg * K3A_SEG + row * 16;
    }
    size_t gB[2]; int lwB[2];
#pragma unroll
    for (int i = 0; i < 2; i++) {
        int e = tid + 256 * i, row = e >> 3, sg = (e + row) & 7;
        gB[i] = (size_t)row * 2304 + sg * 16;
        lwB[i] = K3_BOFF + sg * K3B_SEG + row * 16;
    }

    i32x4 ra[4], rb[2];
#pragma unroll
    for (int i = 0; i < 4; i++) ra[i] = *(const i32x4*)(Ab + gA[i]);
#pragma unroll
    for (int i = 0; i < 2; i++) rb[i] = *(const i32x4*)(Bb + gB[i]);

    int l = tid & 63, wid = tid >> 6;
    int lrow = l & 31, kh = l >> 5;
    int raddrA = kh * K3A_SEG + (wid * 32 + lrow) * 16;
    int raddrB0 = K3_BOFF + kh * K3B_SEG + lrow * 16;
    int raddrB1 = raddrB0 + 32 * 16;

    i32x16 acc0 = {0};
    i32x16 acc1 = {0};
    for (int t = 0; t < 18; ++t) {
        if (t) __syncthreads();
#pragma unroll
        for (int i = 0; i < 4; i++) *(i32x4*)(s + lwA[i]) = ra[i];
#pragma unroll
        for (int i = 0; i < 2; i++) *(i32x4*)(s + lwB[i]) = rb[i];
        if (t < 17) {
            size_t ko = (size_t)(t + 1) * 128;
#pragma unroll
            for (int i = 0; i < 4; i++) ra[i] = *(const i32x4*)(Ab + gA[i] + ko);
#pragma unroll
            for (int i = 0; i < 2; i++) rb[i] = *(const i32x4*)(Bb + gB[i] + ko);
        }
        __syncthreads();
#pragma unroll
        for (int ks = 0; ks < 4; ++ks) {
            i32x4 a  = *(const i32x4*)(s + raddrA + ks * 2 * K3A_SEG);
            i32x4 b0 = *(const i32x4*)(s + raddrB0 + ks * 2 * K3B_SEG);
            i32x4 b1 = *(const i32x4*)(s + raddrB1 + ks * 2 * K3B_SEG);
            acc0 = __builtin_amdgcn_mfma_i32_32x32x32_i8(a, b0, acc0, 0, 0, 0);
            acc1 = __builtin_amdgcn_mfma_i32_32x32x32_i8(a, b1, acc1, 0, 0, 0);
        }
    }

    int col0 = tn * 64 + lrow;
    int col1 = col0 + 32;
    float bi0 = bf1[col0], m0 = mf1[col0];
    float sc0 = gf1[col0] / sqrtf(vf1[col0] + 1e-5f), bb0 = bef1[col0];
    float bi1 = bf1[col1], m1 = mf1[col1];
    float sc1 = gf1[col1] / sqrtf(vf1[col1] + 1e-5f), bb1 = bef1[col1];
    __syncthreads();   // K-loop reads of s done -> reuse as output tile [128][64]
#pragma unroll
    for (int r = 0; r < 16; r++) {
        int rowl = wid * 32 + (r & 3) + 8 * (r >> 2) + 4 * kh;
        float bn0 = ((float)acc0[r] + bi0 - m0) * sc0 + bb0;
        float bn1 = ((float)acc1[r] + bi1 - m1) * sc1 + bb1;
        s[rowl * 64 + lrow] = (signed char)fsign(bn0);
        s[rowl * 64 + lrow + 32] = (signed char)fsign(bn1);
    }
    __syncthreads();
    for (int i = tid; i < 512; i += 256) {
        int rl = i >> 2, c16 = i & 3;
        *(i32x4*)(act3 + (size_t)(tm * 128 + rl) * 1024 + tn * 64 + c16 * 16) =
            *(const i32x4*)(s + i * 16);
    }
}

// K4: fc2 (1024->10) + bias + BN + log_softmax. One wave per image. (unchanged)
__global__ void k4_fc2(const signed char* __restrict__ act3, const signed char* __restrict__ swf2,
                       const float* __restrict__ bf2, const float* __restrict__ gf2,
                       const float* __restrict__ bef2, const float* __restrict__ mf2,
                       const float* __restrict__ vf2, float* __restrict__ out) {
    int wid = (blockIdx.x * 256 + threadIdx.x) >> 6;
    int lane = threadIdx.x & 63;
    if (wid >= BATCH) return;
    const int* hd = (const int*)act3 + (size_t)wid * 256;
    const int* wd = (const int*)swf2;
    int acc[10];
#pragma unroll
    for (int o = 0; o < 10; o++) acc[o] = 0;
#pragma unroll
    for (int i = 0; i < 4; i++) {
        int k4 = i * 64 + lane;
        int hv = hd[k4];
#pragma unroll
        for (int o = 0; o < 10; o++)
            acc[o] = sdot4(hv, wd[o * 256 + k4], acc[o]);
    }
#pragma unroll
    for (int o = 0; o < 10; o++)
#pragma unroll
        for (int s = 32; s > 0; s >>= 1) acc[o] += __shfl_xor(acc[o], s);
    if (lane == 0) {
        float logit[10];
        float mx = -1e30f;
#pragma unroll
        for (int o = 0; o < 10; o++) {
            float z = (float)acc[o] + bf2[o];
            float bn = (z - mf2[o]) * (gf2[o] / sqrtf(vf2[o] + 1e-5f)) + bef2[o];
            logit[o] = bn;
            mx = fmaxf(mx, bn);
        }
        float s = 0.f;
#pragma unroll
        for (int o = 0; o < 10; o++) s += expf(logit[o] - mx);
        float lse = mx + logf(s);
#pragma unroll
        for (int o = 0; o < 10; o++) out[(size_t)wid * 10 + o] = logit[o] - lse;
    }
}

extern "C" void kernel_launch(void* const* d_in, const int* in_sizes, int n_in,
                              void* d_out, int out_size, void* d_ws, size_t ws_size,
                              hipStream_t stream) {
    const float* x   = (const float*)d_in[0];
    const float* w1  = (const float*)d_in[1];
    const float* b1  = (const float*)d_in[2];
    const float* g1  = (const float*)d_in[3];
    const float* be1 = (const float*)d_in[4];
    const float* m1  = (const float*)d_in[5];
    const float* v1  = (const float*)d_in[6];
    const float* w2  = (const float*)d_in[7];
    const float* b2  = (const float*)d_in[8];
    const float* g2  = (const float*)d_in[9];
    const float* be2 = (const float*)d_in[10];
    const float* m2  = (const float*)d_in[11];
    const float* v2  = (const float*)d_in[12];
    const float* wf1 = (const float*)d_in[13];
    const float* bf1 = (const float*)d_in[14];
    const float* gf1 = (const float*)d_in[15];
    const float* bef1= (const float*)d_in[16];
    const float* mf1 = (const float*)d_in[17];
    const float* vf1 = (const float*)d_in[18];
    const float* wf2 = (const float*)d_in[19];
    const float* bf2 = (const float*)d_in[20];
    const float* gf2 = (const float*)d_in[21];
    const float* bef2= (const float*)d_in[22];
    const float* mf2 = (const float*)d_in[23];
    const float* vf2 = (const float*)d_in[24];
    float* out = (float*)d_out;

    // ws layout (all int8)
    char* ws = (char*)d_ws;
    signed char* act1 = (signed char*)ws;                  // 2048*9248     = 18,939,904
    signed char* act2 = act1 + 18939904;                   // 2048*2304     =  4,718,592
    signed char* act3 = act2 + 4718592;                    // 2048*1024     =  2,097,152
    signed char* w2p  = act3 + 2097152;                    // 25*2*64*16    =     51,200
    signed char* wf1s = w2p + 51200;                       // 1024*2304     =  2,359,296
    signed char* wf2p = wf1s + 2359296;                    // 10*1024       =     10,240

    k1_prep<<<2048, 256, 0, stream>>>(x, w1, b1, g1, be1, m1, v1, w2, wf1, wf2,
                                      w2p, wf1s, wf2p, act1);

    k2_mfma<<<256, 768, 0, stream>>>(act1, w2p, b2, g2, be2, m2, v2, act2);

    k3_mfma<<<256, 256, 0, stream>>>(act2, wf1s, bf1, gf1, bef1, mf1, vf1, act3);

    k4_fc2<<<512, 256, 0, stream>>>(act3, wf2p, bf2, gf2, bef2, mf2, vf2, out);
}

// Round 26
// 64.377 us; speedup vs baseline: 1.5040x; 1.0231x over previous
//
#include <hip/hip_runtime.h>
#include <math.h>

#define BATCH 2048

typedef __attribute__((ext_vector_type(4))) int i32x4;
typedef __attribute__((ext_vector_type(16))) int i32x16;
typedef __attribute__((ext_vector_type(2))) float f32x2;

__device__ __forceinline__ int sdot4(int a, int b, int c) {
    return __builtin_amdgcn_sdot4(a, b, c, false);
}

__device__ __forceinline__ float fsign(float v) {
    return v > 0.f ? 1.f : (v < 0.f ? -1.f : 0.f);
}

// act swizzle (T2): flips addr bits 4-6 by pixel bits 2-4; bijective on [0,9248),
// keeps 16B chunks intact, independent of the low 5 bits (oc).
__device__ __forceinline__ int aswz(int off) {
    return off ^ (((off >> 7) & 7) << 4);
}

// K1 + prep fused. 512 threads/image: thread = (oc, py), one pool-row each,
// sliding-window pk-FMA (r25 chains, bit-identical). Sign bytes land in a
// small LDS buffer [169][32]; one cooperative pass applies pad+aswz and does
// fully-coalesced 16B global writes.
__global__ __launch_bounds__(512) void k1_prep(
        const float* __restrict__ x,
        const float* __restrict__ w1, const float* __restrict__ b1,
        const float* __restrict__ g1, const float* __restrict__ be1,
        const float* __restrict__ m1, const float* __restrict__ v1,
        const float* __restrict__ w2, const float* __restrict__ wf1,
        const float* __restrict__ wf2,
        signed char* __restrict__ w2p, signed char* __restrict__ wf1s,
        signed char* __restrict__ wf2p, signed char* __restrict__ act1) {
    __shared__ __align__(16) signed char lact[5408];   // [169 cells][32 oc]
    int b = blockIdx.x, tid = threadIdx.x;

    // ---- prep slice: 1182 elements ----
    {
        int base = b * 1182;
        for (int t = tid; t < 1182; t += 512) {
            int i = base + t;
            if (i < 2359296) {                  // wf1 sign (natural layout)
                float v = wf1[i];
                wf1s[i] = v > 0.f ? 1 : (v < 0.f ? -1 : 0);
            } else if (i < 2359296 + 51200) {   // w2p [tap][half][oc][16]
                int ii = i - 2359296;
                int tap = ii >> 11;
                int r = ii & 2047;
                int half = r >> 10;
                int r2 = r & 1023;
                int oc = r2 >> 4, j = r2 & 15;
                int ic = half * 16 + j;
                float v = w2[(oc * 32 + ic) * 25 + tap];
                w2p[ii] = v > 0.f ? 1 : (v < 0.f ? -1 : 0);
            } else {                            // wf2 sign
                int ii = i - 2359296 - 51200;
                float v = wf2[ii];
                wf2p[ii] = v > 0.f ? 1 : (v < 0.f ? -1 : 0);
            }
        }
    }

    signed char* img = act1 + (size_t)b * 9248;
    // zero the 120 border pixels (240 x 16B chunks); disjoint from interior
    i32x4 z4 = {0, 0, 0, 0};
    if (tid < 240) {
        int pi = tid >> 1, half = tid & 1;
        int p;
        if (pi < 34) p = pi;                       // rows 0-1
        else if (pi < 68) p = 255 + (pi - 34);     // rows 15-16
        else {                                     // rows 2-14, cols 0,1,15,16
            int j2 = pi - 68;
            int row = 2 + (j2 >> 2), c = j2 & 3;
            int col = (c < 2) ? c : 13 + c;        // 0,1,15,16
            p = row * 17 + col;
        }
        *(i32x4*)(img + aswz(p * 32 + half * 16)) = z4;
    }

    // ---- conv1 + BN + sign + pool2 (sliding-window, packed-FMA) -> LDS ----
    int oc = tid & 31, py = tid >> 5;   // py 0..15; rows >=13 idle
    if (py < 13) {
        float sw[9];
#pragma unroll
        for (int i = 0; i < 9; i++) sw[i] = fsign(w1[oc * 9 + i]);
        float bias = b1[oc], m = m1[oc];
        float sc = g1[oc] / sqrtf(v1[oc] + 1e-5f), bb = be1[oc];
        const float* rowp = x + (size_t)b * 784 + py * 56;   // conv row 2py
        signed char* lrow = lact + py * 13 * 32 + oc;

        f32x2 lo[4], hi[4];
#pragma unroll
        for (int dy = 0; dy < 4; dy++) {
            lo[dy] = *(const f32x2*)(rowp + dy * 28);      // cols 0,1
            hi[dy] = *(const f32x2*)(rowp + dy * 28 + 2);  // cols 2,3
        }
#pragma unroll
        for (int px = 0; px < 13; px++) {
            f32x2 pm[4];
#pragma unroll
            for (int dy = 0; dy < 4; dy++) {
                pm[dy].x = lo[dy].y;          // cols 2px+1, 2px+2
                pm[dy].y = hi[dy].x;
            }
            f32x2 a01 = {0.f, 0.f};   // dyp = 0 (rows 0..2)
            f32x2 a23 = {0.f, 0.f};   // dyp = 1 (rows 1..3)
#pragma unroll
            for (int ky = 0; ky < 3; ky++) {
                a01 += lo[ky] * sw[ky * 3 + 0];
                a01 += pm[ky] * sw[ky * 3 + 1];
                a01 += hi[ky] * sw[ky * 3 + 2];
                a23 += lo[ky + 1] * sw[ky * 3 + 0];
                a23 += pm[ky + 1] * sw[ky * 3 + 1];
                a23 += hi[ky + 1] * sw[ky * 3 + 2];
            }
            float maxacc = fmaxf(fmaxf(a01.x, a01.y), fmaxf(a23.x, a23.y));
            float bn = (maxacc + bias - m) * sc + bb;  // same assoc as r25
            lrow[px * 32] = (signed char)fsign(bn);
            if (px < 12) {
#pragma unroll
                for (int dy = 0; dy < 4; dy++) {
                    lo[dy] = hi[dy];          // rotation: no loads re-done
                    hi[dy] = *(const f32x2*)(rowp + dy * 28 + 2 * px + 4);
                }
            }
        }
    }
    __syncthreads();

    // ---- copy-out: pad+aswz mapping, coalesced 16B global writes ----
    if (tid < 338) {
        int pix = tid >> 1, half = tid & 1;
        int py2 = pix / 13, px2 = pix - py2 * 13;
        int p = (py2 + 2) * 17 + (px2 + 2);
        *(i32x4*)(img + aswz(p * 32 + half * 16)) =
            *(const i32x4*)(lact + pix * 32 + half * 16);
    }
}

// K2: conv2 implicit-GEMM MFMA i8. Block = 8 images, 12 waves (768 thr).
// Grid = 256 = 1 block/CU. Staging = pure linear copy. (r25 verbatim)
#define K2_IMG_STRIDE 9248          // 17*17*32
#define K2_WOFF 73984               // 8*9248
__global__ __launch_bounds__(768) void k2_mfma(
        const signed char* __restrict__ act1, const signed char* __restrict__ w2p,
        const float* __restrict__ b2, const float* __restrict__ g2,
        const float* __restrict__ be2, const float* __restrict__ m2,
        const float* __restrict__ v2, signed char* __restrict__ act2) {
    __shared__ __align__(16) signed char smem[125184];
    int tid = threadIdx.x;
    int b0 = blockIdx.x * 8;

    {
        const i32x4* asrc = (const i32x4*)(act1 + (size_t)b0 * 9248);
        i32x4* s4 = (i32x4*)smem;
        for (int i = tid; i < 4624; i += 768) s4[i] = asrc[i];
        const i32x4* wsrc = (const i32x4*)w2p;
        i32x4* w4 = (i32x4*)(smem + K2_WOFF);
        for (int i = tid; i < 3200; i += 768) w4[i] = wsrc[i];
    }
    __syncthreads();

    int wave = tid >> 6, lane = tid & 63;
    int lrow = lane & 31, kh = lane >> 5;
    const signed char* wbase = smem + K2_WOFF + kh * 1024 + lrow * 16;

    const signed char* aimg[3];
    int pixbase[3];
#pragma unroll
    for (int t = 0; t < 3; ++t) {
        int mt = wave * 3 + t;                // 0..35
        int m = mt * 32 + lrow;
        int q = m >> 2, j = m & 3;
        int img = q / 36, qq = q - img * 36;
        int oy = 2 * (qq / 6) + (j >> 1);
        int ox = 2 * (qq - (qq / 6) * 6) + (j & 1);
        aimg[t] = smem + img * K2_IMG_STRIDE;
        pixbase[t] = oy * 17 + ox;
    }

    i32x16 acc[3][2] = {};
#pragma unroll 5
    for (int tap = 0; tap < 25; ++tap) {
        int ky = tap / 5, kx = tap - (tap / 5) * 5;
        i32x4 w0 = *(const i32x4*)(wbase + tap * 2048);        // oc = lrow
        i32x4 w1v = *(const i32x4*)(wbase + tap * 2048 + 512); // oc = 32+lrow
#pragma unroll
        for (int t = 0; t < 3; ++t) {
            int off = (pixbase[t] + ky * 17 + kx) * 32 + kh * 16;
            i32x4 a = *(const i32x4*)(aimg[t] + aswz(off));
            acc[t][0] = __builtin_amdgcn_mfma_i32_32x32x32_i8(a, w0, acc[t][0], 0, 0, 0);
            acc[t][1] = __builtin_amdgcn_mfma_i32_32x32x32_i8(a, w1v, acc[t][1], 0, 0, 0);
        }
    }
    __syncthreads();   // all LDS A/W reads done -> act region reusable

    float bi[2], mm2[2], sc2[2], bb2[2];
#pragma unroll
    for (int h = 0; h < 2; ++h) {
        int oc = h * 32 + lrow;
        bi[h] = b2[oc]; mm2[h] = m2[oc];
        sc2[h] = g2[oc] / sqrtf(v2[oc] + 1e-5f); bb2[h] = be2[oc];
    }
#pragma unroll
    for (int t = 0; t < 3; ++t) {
        int mt = wave * 3 + t;
#pragma unroll
        for (int h = 0; h < 2; ++h) {
            int oc = h * 32 + lrow;
#pragma unroll
            for (int g = 0; g < 4; g++) {
                int qo = mt * 8 + kh + 2 * g;     // pool cell 0..287 (8 images)
                int imo = qo / 36, qqo = qo - imo * 36;
                float best = -2.f;
#pragma unroll
                for (int jj = 0; jj < 4; jj++) {
                    float z = (float)acc[t][h][g * 4 + jj] + bi[h];
                    float bn = (z - mm2[h]) * sc2[h] + bb2[h];
                    best = fmaxf(best, fsign(bn));
                }
                smem[imo * 2304 + oc * 36 + qqo] = (signed char)best;
            }
        }
    }
    __syncthreads();
    {
        const i32x4* s4o = (const i32x4*)smem;
        i32x4* dst = (i32x4*)(act2 + (size_t)b0 * 2304);
        for (int i = tid; i < 1152; i += 768) dst[i] = s4o[i];
    }
}

// K3: fc1 as LDS-tiled MFMA i8 GEMM 2048x1024x2304. (r25 verbatim)
#define K3A_SEG 2064                // 128*16 + 16 pad
#define K3B_SEG 1040                // 64*16 + 16 pad
#define K3_BOFF 16512               // 8 * 2064
__global__ __launch_bounds__(256) void k3_mfma(
        const signed char* __restrict__ act2, const signed char* __restrict__ wf1s,
        const float* __restrict__ bf1, const float* __restrict__ gf1,
        const float* __restrict__ bef1, const float* __restrict__ mf1,
        const float* __restrict__ vf1, signed char* __restrict__ act3) {
    __shared__ __align__(16) signed char s[K3_BOFF + 8 * K3B_SEG];  // 24832
    int tid = threadIdx.x;
    int bid = blockIdx.x;
    int tn = bid & 15, tm = bid >> 4;

    const signed char* Ab = act2 + (size_t)tm * 128 * 2304;
    const signed char* Bb = wf1s + (size_t)tn * 64 * 2304;
    size_t gA[4]; int lwA[4];
#pragma unroll
    for (int i = 0; i < 4; i++) {
        int e = tid + 256 * i, row = e >> 3, sg = (e + row) & 7;
        gA[i] = (size_t)row * 2304 + sg * 16;
        lwA[i] = sg * K3A_SEG + row * 16;
    }
    size_t gB[2]; int lwB[2];
#pragma unroll
    for (int i = 0; i < 2; i++) {
        int e = tid + 256 * i, row = e >> 3, sg = (e + row) & 7;
        gB[i] = (size_t)row * 2304 + sg * 16;
        lwB[i] = K3_BOFF + sg * K3B_SEG + row * 16;
    }

    i32x4 ra[4], rb[2];
#pragma unroll
    for (int i = 0; i < 4; i++) ra[i] = *(const i32x4*)(Ab + gA[i]);
#pragma unroll
    for (int i = 0; i < 2; i++) rb[i] = *(const i32x4*)(Bb + gB[i]);

    int l = tid & 63, wid = tid >> 6;
    int lrow = l & 31, kh = l >> 5;
    int raddrA = kh * K3A_SEG + (wid * 32 + lrow) * 16;
    int raddrB0 = K3_BOFF + kh * K3B_SEG + lrow * 16;
    int raddrB1 = raddrB0 + 32 * 16;

    i32x16 acc0 = {0};
    i32x16 acc1 = {0};
    for (int t = 0; t < 18; ++t) {
        if (t) __syncthreads();
#pragma unroll
        for (int i = 0; i < 4; i++) *(i32x4*)(s + lwA[i]) = ra[i];
#pragma unroll
        for (int i = 0; i < 2; i++) *(i32x4*)(s + lwB[i]) = rb[i];
        if (t < 17) {
            size_t ko = (size_t)(t + 1) * 128;
#pragma unroll
            for (int i = 0; i < 4; i++) ra[i] = *(const i32x4*)(Ab + gA[i] + ko);
#pragma unroll
            for (int i = 0; i < 2; i++) rb[i] = *(const i32x4*)(Bb + gB[i] + ko);
        }
        __syncthreads();
#pragma unroll
        for (int ks = 0; ks < 4; ++ks) {
            i32x4 a  = *(const i32x4*)(s + raddrA + ks * 2 * K3A_SEG);
            i32x4 b0 = *(const i32x4*)(s + raddrB0 + ks * 2 * K3B_SEG);
            i32x4 b1 = *(const i32x4*)(s + raddrB1 + ks * 2 * K3B_SEG);
            acc0 = __builtin_amdgcn_mfma_i32_32x32x32_i8(a, b0, acc0, 0, 0, 0);
            acc1 = __builtin_amdgcn_mfma_i32_32x32x32_i8(a, b1, acc1, 0, 0, 0);
        }
    }

    int col0 = tn * 64 + lrow;
    int col1 = col0 + 32;
    float bi0 = bf1[col0], m0 = mf1[col0];
    float sc0 = gf1[col0] / sqrtf(vf1[col0] + 1e-5f), bb0 = bef1[col0];
    float bi1 = bf1[col1], m1 = mf1[col1];
    float sc1 = gf1[col1] / sqrtf(vf1[col1] + 1e-5f), bb1 = bef1[col1];
    __syncthreads();   // K-loop reads of s done -> reuse as output tile [128][64]
#pragma unroll
    for (int r = 0; r < 16; r++) {
        int rowl = wid * 32 + (r & 3) + 8 * (r >> 2) + 4 * kh;
        float bn0 = ((float)acc0[r] + bi0 - m0) * sc0 + bb0;
        float bn1 = ((float)acc1[r] + bi1 - m1) * sc1 + bb1;
        s[rowl * 64 + lrow] = (signed char)fsign(bn0);
        s[rowl * 64 + lrow + 32] = (signed char)fsign(bn1);
    }
    __syncthreads();
    for (int i = tid; i < 512; i += 256) {
        int rl = i >> 2, c16 = i & 3;
        *(i32x4*)(act3 + (size_t)(tm * 128 + rl) * 1024 + tn * 64 + c16 * 16) =
            *(const i32x4*)(s + i * 16);
    }
}

// K4: fc2 (1024->10) + bias + BN + log_softmax. One wave per image. (unchanged)
__global__ void k4_fc2(const signed char* __restrict__ act3, const signed char* __restrict__ swf2,
                       const float* __restrict__ bf2, const float* __restrict__ gf2,
                       const float* __restrict__ bef2, const float* __restrict__ mf2,
                       const float* __restrict__ vf2, float* __restrict__ out) {
    int wid = (blockIdx.x * 256 + threadIdx.x) >> 6;
    int lane = threadIdx.x & 63;
    if (wid >= BATCH) return;
    const int* hd = (const int*)act3 + (size_t)wid * 256;
    const int* wd = (const int*)swf2;
    int acc[10];
#pragma unroll
    for (int o = 0; o < 10; o++) acc[o] = 0;
#pragma unroll
    for (int i = 0; i < 4; i++) {
        int k4 = i * 64 + lane;
        int hv = hd[k4];
#pragma unroll
        for (int o = 0; o < 10; o++)
            acc[o] = sdot4(hv, wd[o * 256 + k4], acc[o]);
    }
#pragma unroll
    for (int o = 0; o < 10; o++)
#pragma unroll
        for (int s = 32; s > 0; s >>= 1) acc[o] += __shfl_xor(acc[o], s);
    if (lane == 0) {
        float logit[10];
        float mx = -1e30f;
#pragma unroll
        for (int o = 0; o < 10; o++) {
            float z = (float)acc[o] + bf2[o];
            float bn = (z - mf2[o]) * (gf2[o] / sqrtf(vf2[o] + 1e-5f)) + bef2[o];
            logit[o] = bn;
            mx = fmaxf(mx, bn);
        }
        float s = 0.f;
#pragma unroll
        for (int o = 0; o < 10; o++) s += expf(logit[o] - mx);
        float lse = mx + logf(s);
#pragma unroll
        for (int o = 0; o < 10; o++) out[(size_t)wid * 10 + o] = logit[o] - lse;
    }
}

extern "C" void kernel_launch(void* const* d_in, const int* in_sizes, int n_in,
                              void* d_out, int out_size, void* d_ws, size_t ws_size,
                              hipStream_t stream) {
    const float* x   = (const float*)d_in[0];
    const float* w1  = (const float*)d_in[1];
    const float* b1  = (const float*)d_in[2];
    const float* g1  = (const float*)d_in[3];
    const float* be1 = (const float*)d_in[4];
    const float* m1  = (const float*)d_in[5];
    const float* v1  = (const float*)d_in[6];
    const float* w2  = (const float*)d_in[7];
    const float* b2  = (const float*)d_in[8];
    const float* g2  = (const float*)d_in[9];
    const float* be2 = (const float*)d_in[10];
    const float* m2  = (const float*)d_in[11];
    const float* v2  = (const float*)d_in[12];
    const float* wf1 = (const float*)d_in[13];
    const float* bf1 = (const float*)d_in[14];
    const float* gf1 = (const float*)d_in[15];
    const float* bef1= (const float*)d_in[16];
    const float* mf1 = (const float*)d_in[17];
    const float* vf1 = (const float*)d_in[18];
    const float* wf2 = (const float*)d_in[19];
    const float* bf2 = (const float*)d_in[20];
    const float* gf2 = (const float*)d_in[21];
    const float* bef2= (const float*)d_in[22];
    const float* mf2 = (const float*)d_in[23];
    const float* vf2 = (const float*)d_in[24];
    float* out = (float*)d_out;

    // ws layout (all int8)
    char* ws = (char*)d_ws;
    signed char* act1 = (signed char*)ws;                  // 2048*9248     = 18,939,904
    signed char* act2 = act1 + 18939904;                   // 2048*2304     =  4,718,592
    signed char* act3 = act2 + 4718592;                    // 2048*1024     =  2,097,152
    signed char* w2p  = act3 + 2097152;                    // 25*2*64*16    =     51,200
    signed char* wf1s = w2p + 51200;                       // 1024*2304     =  2,359,296
    signed char* wf2p = wf1s + 2359296;                    // 10*1024       =     10,240

    k1_prep<<<2048, 512, 0, stream>>>(x, w1, b1, g1, be1, m1, v1, w2, wf1, wf2,
                                      w2p, wf1s, wf2p, act1);

    k2_mfma<<<256, 768, 0, stream>>>(act1, w2p, b2, g2, be2, m2, v2, act2);

    k3_mfma<<<256, 256, 0, stream>>>(act2, wf1s, bf1, gf1, bef1, mf1, vf1, act3);

    k4_fc2<<<512, 256, 0, stream>>>(act3, wf2p, bf2, gf2, bef2, mf2, vf2, out);
}

// Round 27
// 60.343 us; speedup vs baseline: 1.6045x; 1.0668x over previous
//
#include <hip/hip_runtime.h>
#include <math.h>

#define BATCH 2048

typedef __attribute__((ext_vector_type(4))) int i32x4;
typedef __attribute__((ext_vector_type(16))) int i32x16;
typedef __attribute__((ext_vector_type(2))) float f32x2;

__device__ __forceinline__ int sdot4(int a, int b, int c) {
    return __builtin_amdgcn_sdot4(a, b, c, false);
}

__device__ __forceinline__ float fsign(float v) {
    return v > 0.f ? 1.f : (v < 0.f ? -1.f : 0.f);
}

// act swizzle (T2): flips addr bits 4-6 by pixel bits 2-4; bijective on [0,9248),
// keeps 16B chunks intact, independent of the low 5 bits (oc).
__device__ __forceinline__ int aswz(int off) {
    return off ^ (((off >> 7) & 7) << 4);
}

// K1 + prep fused. 512 threads/image. x staged in LDS (196 coalesced float4),
// then sliding-window pk-FMA per (oc, py) reading f32x2 from LDS (broadcast,
// ~30cyc) -> kills the serial global-load chain. lact buffer + coalesced
// copy-out as r26. Conv arithmetic byte-identical -> bit-identical output.
__global__ __launch_bounds__(512) void k1_prep(
        const float* __restrict__ x,
        const float* __restrict__ w1, const float* __restrict__ b1,
        const float* __restrict__ g1, const float* __restrict__ be1,
        const float* __restrict__ m1, const float* __restrict__ v1,
        const float* __restrict__ w2, const float* __restrict__ wf1,
        const float* __restrict__ wf2,
        signed char* __restrict__ w2p, signed char* __restrict__ wf1s,
        signed char* __restrict__ wf2p, signed char* __restrict__ act1) {
    __shared__ __align__(16) float xs[784];
    __shared__ __align__(16) signed char lact[5408];   // [169 cells][32 oc]
    int b = blockIdx.x, tid = threadIdx.x;

    // stage image (coalesced float4)
    if (tid < 196) ((float4*)xs)[tid] = ((const float4*)(x + (size_t)b * 784))[tid];

    // ---- prep slice: 1182 elements (global->global; overlaps staging wait) ----
    {
        int base = b * 1182;
        for (int t = tid; t < 1182; t += 512) {
            int i = base + t;
            if (i < 2359296) {                  // wf1 sign (natural layout)
                float v = wf1[i];
                wf1s[i] = v > 0.f ? 1 : (v < 0.f ? -1 : 0);
            } else if (i < 2359296 + 51200) {   // w2p [tap][half][oc][16]
                int ii = i - 2359296;
                int tap = ii >> 11;
                int r = ii & 2047;
                int half = r >> 10;
                int r2 = r & 1023;
                int oc = r2 >> 4, j = r2 & 15;
                int ic = half * 16 + j;
                float v = w2[(oc * 32 + ic) * 25 + tap];
                w2p[ii] = v > 0.f ? 1 : (v < 0.f ? -1 : 0);
            } else {                            // wf2 sign
                int ii = i - 2359296 - 51200;
                float v = wf2[ii];
                wf2p[ii] = v > 0.f ? 1 : (v < 0.f ? -1 : 0);
            }
        }
    }

    signed char* img = act1 + (size_t)b * 9248;
    // zero the 120 border pixels (240 x 16B chunks); disjoint from interior
    i32x4 z4 = {0, 0, 0, 0};
    if (tid < 240) {
        int pi = tid >> 1, half = tid & 1;
        int p;
        if (pi < 34) p = pi;                       // rows 0-1
        else if (pi < 68) p = 255 + (pi - 34);     // rows 15-16
        else {                                     // rows 2-14, cols 0,1,15,16
            int j2 = pi - 68;
            int row = 2 + (j2 >> 2), c = j2 & 3;
            int col = (c < 2) ? c : 13 + c;        // 0,1,15,16
            p = row * 17 + col;
        }
        *(i32x4*)(img + aswz(p * 32 + half * 16)) = z4;
    }
    __syncthreads();   // xs ready

    // ---- conv1 + BN + sign + pool2 (sliding-window, packed-FMA, LDS x) ----
    int oc = tid & 31, py = tid >> 5;   // py 0..15; rows >=13 idle
    if (py < 13) {
        float sw[9];
#pragma unroll
        for (int i = 0; i < 9; i++) sw[i] = fsign(w1[oc * 9 + i]);
        float bias = b1[oc], m = m1[oc];
        float sc = g1[oc] / sqrtf(v1[oc] + 1e-5f), bb = be1[oc];
        const float* rowp = xs + py * 56;   // conv row 2py (LDS)
        signed char* lrow = lact + py * 13 * 32 + oc;

        f32x2 lo[4], hi[4];
#pragma unroll
        for (int dy = 0; dy < 4; dy++) {
            lo[dy] = *(const f32x2*)(rowp + dy * 28);      // cols 0,1
            hi[dy] = *(const f32x2*)(rowp + dy * 28 + 2);  // cols 2,3
        }
#pragma unroll
        for (int px = 0; px < 13; px++) {
            f32x2 pm[4];
#pragma unroll
            for (int dy = 0; dy < 4; dy++) {
                pm[dy].x = lo[dy].y;          // cols 2px+1, 2px+2
                pm[dy].y = hi[dy].x;
            }
            f32x2 a01 = {0.f, 0.f};   // dyp = 0 (rows 0..2)
            f32x2 a23 = {0.f, 0.f};   // dyp = 1 (rows 1..3)
#pragma unroll
            for (int ky = 0; ky < 3; ky++) {
                a01 += lo[ky] * sw[ky * 3 + 0];
                a01 += pm[ky] * sw[ky * 3 + 1];
                a01 += hi[ky] * sw[ky * 3 + 2];
                a23 += lo[ky + 1] * sw[ky * 3 + 0];
                a23 += pm[ky + 1] * sw[ky * 3 + 1];
                a23 += hi[ky + 1] * sw[ky * 3 + 2];
            }
            float maxacc = fmaxf(fmaxf(a01.x, a01.y), fmaxf(a23.x, a23.y));
            float bn = (maxacc + bias - m) * sc + bb;  // same assoc as r26
            lrow[px * 32] = (signed char)fsign(bn);
            if (px < 12) {
#pragma unroll
                for (int dy = 0; dy < 4; dy++) {
                    lo[dy] = hi[dy];          // rotation: no loads re-done
                    hi[dy] = *(const f32x2*)(rowp + dy * 28 + 2 * px + 4);
                }
            }
        }
    }
    __syncthreads();

    // ---- copy-out: pad+aswz mapping, coalesced 16B global writes ----
    if (tid < 338) {
        int pix = tid >> 1, half = tid & 1;
        int py2 = pix / 13, px2 = pix - py2 * 13;
        int p = (py2 + 2) * 17 + (px2 + 2);
        *(i32x4*)(img + aswz(p * 32 + half * 16)) =
            *(const i32x4*)(lact + pix * 32 + half * 16);
    }
}

// K2: conv2 implicit-GEMM MFMA i8. Block = 8 images, 12 waves (768 thr).
// Grid = 256 = 1 block/CU. Staging = pure linear copy. (r26 verbatim)
#define K2_IMG_STRIDE 9248          // 17*17*32
#define K2_WOFF 73984               // 8*9248
__global__ __launch_bounds__(768) void k2_mfma(
        const signed char* __restrict__ act1, const signed char* __restrict__ w2p,
        const float* __restrict__ b2, const float* __restrict__ g2,
        const float* __restrict__ be2, const float* __restrict__ m2,
        const float* __restrict__ v2, signed char* __restrict__ act2) {
    __shared__ __align__(16) signed char smem[125184];
    int tid = threadIdx.x;
    int b0 = blockIdx.x * 8;

    {
        const i32x4* asrc = (const i32x4*)(act1 + (size_t)b0 * 9248);
        i32x4* s4 = (i32x4*)smem;
        for (int i = tid; i < 4624; i += 768) s4[i] = asrc[i];
        const i32x4* wsrc = (const i32x4*)w2p;
        i32x4* w4 = (i32x4*)(smem + K2_WOFF);
        for (int i = tid; i < 3200; i += 768) w4[i] = wsrc[i];
    }
    __syncthreads();

    int wave = tid >> 6, lane = tid & 63;
    int lrow = lane & 31, kh = lane >> 5;
    const signed char* wbase = smem + K2_WOFF + kh * 1024 + lrow * 16;

    const signed char* aimg[3];
    int pixbase[3];
#pragma unroll
    for (int t = 0; t < 3; ++t) {
        int mt = wave * 3 + t;                // 0..35
        int m = mt * 32 + lrow;
        int q = m >> 2, j = m & 3;
        int img = q / 36, qq = q - img * 36;
        int oy = 2 * (qq / 6) + (j >> 1);
        int ox = 2 * (qq - (qq / 6) * 6) + (j & 1);
        aimg[t] = smem + img * K2_IMG_STRIDE;
        pixbase[t] = oy * 17 + ox;
    }

    i32x16 acc[3][2] = {};
#pragma unroll 5
    for (int tap = 0; tap < 25; ++tap) {
        int ky = tap / 5, kx = tap - (tap / 5) * 5;
        i32x4 w0 = *(const i32x4*)(wbase + tap * 2048);        // oc = lrow
        i32x4 w1v = *(const i32x4*)(wbase + tap * 2048 + 512); // oc = 32+lrow
#pragma unroll
        for (int t = 0; t < 3; ++t) {
            int off = (pixbase[t] + ky * 17 + kx) * 32 + kh * 16;
            i32x4 a = *(const i32x4*)(aimg[t] + aswz(off));
            acc[t][0] = __builtin_amdgcn_mfma_i32_32x32x32_i8(a, w0, acc[t][0], 0, 0, 0);
            acc[t][1] = __builtin_amdgcn_mfma_i32_32x32x32_i8(a, w1v, acc[t][1], 0, 0, 0);
        }
    }
    __syncthreads();   // all LDS A/W reads done -> act region reusable

    float bi[2], mm2[2], sc2[2], bb2[2];
#pragma unroll
    for (int h = 0; h < 2; ++h) {
        int oc = h * 32 + lrow;
        bi[h] = b2[oc]; mm2[h] = m2[oc];
        sc2[h] = g2[oc] / sqrtf(v2[oc] + 1e-5f); bb2[h] = be2[oc];
    }
#pragma unroll
    for (int t = 0; t < 3; ++t) {
        int mt = wave * 3 + t;
#pragma unroll
        for (int h = 0; h < 2; ++h) {
            int oc = h * 32 + lrow;
#pragma unroll
            for (int g = 0; g < 4; g++) {
                int qo = mt * 8 + kh + 2 * g;     // pool cell 0..287 (8 images)
                int imo = qo / 36, qqo = qo - imo * 36;
                float best = -2.f;
#pragma unroll
                for (int jj = 0; jj < 4; jj++) {
                    float z = (float)acc[t][h][g * 4 + jj] + bi[h];
                    float bn = (z - mm2[h]) * sc2[h] + bb2[h];
                    best = fmaxf(best, fsign(bn));
                }
                smem[imo * 2304 + oc * 36 + qqo] = (signed char)best;
            }
        }
    }
    __syncthreads();
    {
        const i32x4* s4o = (const i32x4*)smem;
        i32x4* dst = (i32x4*)(act2 + (size_t)b0 * 2304);
        for (int i = tid; i < 1152; i += 768) dst[i] = s4o[i];
    }
}

// K3: fc1 as LDS-tiled MFMA i8 GEMM 2048x1024x2304. (r26 verbatim)
#define K3A_SEG 2064                // 128*16 + 16 pad
#define K3B_SEG 1040                // 64*16 + 16 pad
#define K3_BOFF 16512               // 8 * 2064
__global__ __launch_bounds__(256) void k3_mfma(
        const signed char* __restrict__ act2, const signed char* __restrict__ wf1s,
        const float* __restrict__ bf1, const float* __restrict__ gf1,
        const float* __restrict__ bef1, const float* __restrict__ mf1,
        const float* __restrict__ vf1, signed char* __restrict__ act3) {
    __shared__ __align__(16) signed char s[K3_BOFF + 8 * K3B_SEG];  // 24832
    int tid = threadIdx.x;
    int bid = blockIdx.x;
    int tn = bid & 15, tm = bid >> 4;

    const signed char* Ab = act2 + (size_t)tm * 128 * 2304;
    const signed char* Bb = wf1s + (size_t)tn * 64 * 2304;
    size_t gA[4]; int lwA[4];
#pragma unroll
    for (int i = 0; i < 4; i++) {
        int e = tid + 256 * i, row = e >> 3, sg = (e + row) & 7;
        gA[i] = (size_t)row * 2304 + sg * 16;
        lwA[i] = sg * K3A_SEG + row * 16;
    }
    size_t gB[2]; int lwB[2];
#pragma unroll
    for (int i = 0; i < 2; i++) {
        int e = tid + 256 * i, row = e >> 3, sg = (e + row) & 7;
        gB[i] = (size_t)row * 2304 + sg * 16;
        lwB[i] = K3_BOFF + sg * K3B_SEG + row * 16;
    }

    i32x4 ra[4], rb[2];
#pragma unroll
    for (int i = 0; i < 4; i++) ra[i] = *(const i32x4*)(Ab + gA[i]);
#pragma unroll
    for (int i = 0; i < 2; i++) rb[i] = *(const i32x4*)(Bb + gB[i]);

    int l = tid & 63, wid = tid >> 6;
    int lrow = l & 31, kh = l >> 5;
    int raddrA = kh * K3A_SEG + (wid * 32 + lrow) * 16;
    int raddrB0 = K3_BOFF + kh * K3B_SEG + lrow * 16;
    int raddrB1 = raddrB0 + 32 * 16;

    i32x16 acc0 = {0};
    i32x16 acc1 = {0};
    for (int t = 0; t < 18; ++t) {
        if (t) __syncthreads();
#pragma unroll
        for (int i = 0; i < 4; i++) *(i32x4*)(s + lwA[i]) = ra[i];
#pragma unroll
        for (int i = 0; i < 2; i++) *(i32x4*)(s + lwB[i]) = rb[i];
        if (t < 17) {
            size_t ko = (size_t)(t + 1) * 128;
#pragma unroll
            for (int i = 0; i < 4; i++) ra[i] = *(const i32x4*)(Ab + gA[i] + ko);
#pragma unroll
            for (int i = 0; i < 2; i++) rb[i] = *(const i32x4*)(Bb + gB[i] + ko);
        }
        __syncthreads();
#pragma unroll
        for (int ks = 0; ks < 4; ++ks) {
            i32x4 a  = *(const i32x4*)(s + raddrA + ks * 2 * K3A_SEG);
            i32x4 b0 = *(const i32x4*)(s + raddrB0 + ks * 2 * K3B_SEG);
            i32x4 b1 = *(const i32x4*)(s + raddrB1 + ks * 2 * K3B_SEG);
            acc0 = __builtin_amdgcn_mfma_i32_32x32x32_i8(a, b0, acc0, 0, 0, 0);
            acc1 = __builtin_amdgcn_mfma_i32_32x32x32_i8(a, b1, acc1, 0, 0, 0);
        }
    }

    int col0 = tn * 64 + lrow;
    int col1 = col0 + 32;
    float bi0 = bf1[col0], m0 = mf1[col0];
    float sc0 = gf1[col0] / sqrtf(vf1[col0] + 1e-5f), bb0 = bef1[col0];
    float bi1 = bf1[col1], m1 = mf1[col1];
    float sc1 = gf1[col1] / sqrtf(vf1[col1] + 1e-5f), bb1 = bef1[col1];
    __syncthreads();   // K-loop reads of s done -> reuse as output tile [128][64]
#pragma unroll
    for (int r = 0; r < 16; r++) {
        int rowl = wid * 32 + (r & 3) + 8 * (r >> 2) + 4 * kh;
        float bn0 = ((float)acc0[r] + bi0 - m0) * sc0 + bb0;
        float bn1 = ((float)acc1[r] + bi1 - m1) * sc1 + bb1;
        s[rowl * 64 + lrow] = (signed char)fsign(bn0);
        s[rowl * 64 + lrow + 32] = (signed char)fsign(bn1);
    }
    __syncthreads();
    for (int i = tid; i < 512; i += 256) {
        int rl = i >> 2, c16 = i & 3;
        *(i32x4*)(act3 + (size_t)(tm * 128 + rl) * 1024 + tn * 64 + c16 * 16) =
            *(const i32x4*)(s + i * 16);
    }
}

// K4: fc2 (1024->10) + bias + BN + log_softmax. One wave per image. (unchanged)
__global__ void k4_fc2(const signed char* __restrict__ act3, const signed char* __restrict__ swf2,
                       const float* __restrict__ bf2, const float* __restrict__ gf2,
                       const float* __restrict__ bef2, const float* __restrict__ mf2,
                       const float* __restrict__ vf2, float* __restrict__ out) {
    int wid = (blockIdx.x * 256 + threadIdx.x) >> 6;
    int lane = threadIdx.x & 63;
    if (wid >= BATCH) return;
    const int* hd = (const int*)act3 + (size_t)wid * 256;
    const int* wd = (const int*)swf2;
    int acc[10];
#pragma unroll
    for (int o = 0; o < 10; o++) acc[o] = 0;
#pragma unroll
    for (int i = 0; i < 4; i++) {
        int k4 = i * 64 + lane;
        int hv = hd[k4];
#pragma unroll
        for (int o = 0; o < 10; o++)
            acc[o] = sdot4(hv, wd[o * 256 + k4], acc[o]);
    }
#pragma unroll
    for (int o = 0; o < 10; o++)
#pragma unroll
        for (int s = 32; s > 0; s >>= 1) acc[o] += __shfl_xor(acc[o], s);
    if (lane == 0) {
        float logit[10];
        float mx = -1e30f;
#pragma unroll
        for (int o = 0; o < 10; o++) {
            float z = (float)acc[o] + bf2[o];
            float bn = (z - mf2[o]) * (gf2[o] / sqrtf(vf2[o] + 1e-5f)) + bef2[o];
            logit[o] = bn;
            mx = fmaxf(mx, bn);
        }
        float s = 0.f;
#pragma unroll
        for (int o = 0; o < 10; o++) s += expf(logit[o] - mx);
        float lse = mx + logf(s);
#pragma unroll
        for (int o = 0; o < 10; o++) out[(size_t)wid * 10 + o] = logit[o] - lse;
    }
}

extern "C" void kernel_launch(void* const* d_in, const int* in_sizes, int n_in,
                              void* d_out, int out_size, void* d_ws, size_t ws_size,
                              hipStream_t stream) {
    const float* x   = (const float*)d_in[0];
    const float* w1  = (const float*)d_in[1];
    const float* b1  = (const float*)d_in[2];
    const float* g1  = (const float*)d_in[3];
    const float* be1 = (const float*)d_in[4];
    const float* m1  = (const float*)d_in[5];
    const float* v1  = (const float*)d_in[6];
    const float* w2  = (const float*)d_in[7];
    const float* b2  = (const float*)d_in[8];
    const float* g2  = (const float*)d_in[9];
    const float* be2 = (const float*)d_in[10];
    const float* m2  = (const float*)d_in[11];
    const float* v2  = (const float*)d_in[12];
    const float* wf1 = (const float*)d_in[13];
    const float* bf1 = (const float*)d_in[14];
    const float* gf1 = (const float*)d_in[15];
    const float* bef1= (const float*)d_in[16];
    const float* mf1 = (const float*)d_in[17];
    const float* vf1 = (const float*)d_in[18];
    const float* wf2 = (const float*)d_in[19];
    const float* bf2 = (const float*)d_in[20];
    const float* gf2 = (const float*)d_in[21];
    const float* bef2= (const float*)d_in[22];
    const float* mf2 = (const float*)d_in[23];
    const float* vf2 = (const float*)d_in[24];
    float* out = (float*)d_out;

    // ws layout (all int8)
    char* ws = (char*)d_ws;
    signed char* act1 = (signed char*)ws;                  // 2048*9248     = 18,939,904
    signed char* act2 = act1 + 18939904;                   // 2048*2304     =  4,718,592
    signed char* act3 = act2 + 4718592;                    // 2048*1024     =  2,097,152
    signed char* w2p  = act3 + 2097152;                    // 25*2*64*16    =     51,200
    signed char* wf1s = w2p + 51200;                       // 1024*2304     =  2,359,296
    signed char* wf2p = wf1s + 2359296;                    // 10*1024       =     10,240

    k1_prep<<<2048, 512, 0, stream>>>(x, w1, b1, g1, be1, m1, v1, w2, wf1, wf2,
                                      w2p, wf1s, wf2p, act1);

    k2_mfma<<<256, 768, 0, stream>>>(act1, w2p, b2, g2, be2, m2, v2, act2);

    k3_mfma<<<256, 256, 0, stream>>>(act2, wf1s, bf1, gf1, bef1, mf1, vf1, act3);

    k4_fc2<<<512, 256, 0, stream>>>(act3, wf2p, bf2, gf2, bef2, mf2, vf2, out);
}